// Round 1
// 2759.277 us; speedup vs baseline: 1.4112x; 1.4112x over previous
//
#include <hip/hip_runtime.h>
#include <math.h>

#define Bz 4
#define Lz 4096
#define Dz 1024
#define Hz 16
#define Cz 8
#define Sz 512
#define DHz 64

typedef __bf16 bf16x8 __attribute__((ext_vector_type(8)));
typedef float f32x16 __attribute__((ext_vector_type(16)));

__device__ __forceinline__ float sigmaf(float x) {
    return x >= 0.f ? x : expm1f(x);
}

// pack two f32 -> one dword of 2 bf16 (RNE), lo = a, hi = b
__device__ __forceinline__ unsigned pkbf(float a, float b) {
    unsigned r;
    asm("v_cvt_pk_bf16_f32 %0, %1, %2" : "=v"(r) : "v"(a), "v"(b));
    return r;
}

// ---------------- QKV projection: out = X @ W + b  (3 GEMMs via blockIdx.z) ----
__global__ __launch_bounds__(256) void proj_kernel(
    const float* __restrict__ Xq, const float* __restrict__ Xk, const float* __restrict__ Xv,
    const float* __restrict__ Wq, const float* __restrict__ bq,
    const float* __restrict__ Wk, const float* __restrict__ bk,
    const float* __restrict__ Wv, const float* __restrict__ bv,
    float* __restrict__ outq, float* __restrict__ outk, float* __restrict__ outv)
{
    const int which = blockIdx.z;
    const float* __restrict__ X = which == 0 ? Xq : (which == 1 ? Xk : Xv);
    const float* __restrict__ W = which == 0 ? Wq : (which == 1 ? Wk : Wv);
    const float* __restrict__ bias = which == 0 ? bq : (which == 1 ? bk : bv);
    float* __restrict__ out = which == 0 ? outq : (which == 1 ? outk : outv);

    __shared__ float As[16][64];   // [k][m]
    __shared__ float Bs[16][64];   // [k][n]
    const int tid = threadIdx.x;
    const int m0 = blockIdx.y * 64;
    const int n0 = blockIdx.x * 64;
    const int tx = tid & 15, ty = tid >> 4;

    float acc[4][4] = {{0.f}};

    const int lm = tid >> 2;          // A row 0..63
    const int lk = (tid & 3) * 4;     // A k 0,4,8,12
    const int br = tid >> 4;          // B row 0..15
    const int bn = (tid & 15) * 4;    // B col

    for (int k0 = 0; k0 < Dz; k0 += 16) {
        float4 a = *(const float4*)&X[(size_t)(m0 + lm) * Dz + k0 + lk];
        float4 b4 = *(const float4*)&W[(size_t)(k0 + br) * Dz + n0 + bn];
        __syncthreads();
        As[lk + 0][lm] = a.x; As[lk + 1][lm] = a.y; As[lk + 2][lm] = a.z; As[lk + 3][lm] = a.w;
        *(float4*)&Bs[br][bn] = b4;
        __syncthreads();
#pragma unroll
        for (int kk = 0; kk < 16; ++kk) {
            float av[4], bv4[4];
            *(float4*)av  = *(const float4*)&As[kk][ty * 4];
            *(float4*)bv4 = *(const float4*)&Bs[kk][tx * 4];
#pragma unroll
            for (int i = 0; i < 4; ++i)
#pragma unroll
                for (int j = 0; j < 4; ++j) acc[i][j] += av[i] * bv4[j];
        }
    }
#pragma unroll
    for (int i = 0; i < 4; ++i) {
        int m = m0 + ty * 4 + i;
        float4 o;
        o.x = acc[i][0] + bias[n0 + tx * 4 + 0];
        o.y = acc[i][1] + bias[n0 + tx * 4 + 1];
        o.z = acc[i][2] + bias[n0 + tx * 4 + 2];
        o.w = acc[i][3] + bias[n0 + tx * 4 + 3];
        *(float4*)&out[(size_t)m * Dz + n0 + tx * 4] = o;
    }
}

// ---------------- V transpose to bf16: vth[b][h][d][L] <- v[b][l][h*64+d] ----
__global__ __launch_bounds__(256) void vt_kernel(
    const float* __restrict__ v, unsigned short* __restrict__ vth)
{
    const int b = blockIdx.z, h = blockIdx.y, l0 = blockIdx.x * 64;
    const int tid = threadIdx.x;
    __shared__ float Ls[64][65];
#pragma unroll
    for (int it = 0; it < 4; ++it) {
        int idx = it * 256 + tid;
        int r = idx >> 4, c4 = (idx & 15) * 4;
        float4 t = *(const float4*)&v[((size_t)b * Lz + l0 + r) * Dz + h * DHz + c4];
        Ls[r][c4] = t.x; Ls[r][c4 + 1] = t.y; Ls[r][c4 + 2] = t.z; Ls[r][c4 + 3] = t.w;
    }
    __syncthreads();
    const int d = tid >> 2, j0 = (tid & 3) * 16;
    unsigned u[8];
#pragma unroll
    for (int j = 0; j < 8; ++j)
        u[j] = pkbf(Ls[j0 + 2 * j][d], Ls[j0 + 2 * j + 1][d]);
    unsigned short* op = vth + ((size_t)(b * Hz + h) * 64 + d) * Lz + l0 + j0;
    uint4 o0; o0.x = u[0]; o0.y = u[1]; o0.z = u[2]; o0.w = u[3];
    uint4 o1; o1.x = u[4]; o1.y = u[5]; o1.z = u[6]; o1.w = u[7];
    *(uint4*)op = o0;
    *(uint4*)(op + 8) = o1;
}

// ---------------- MFMA local attention; writes (1-g)*dot into XT[b][e][l] ----
// block: 256 thr = 4 waves, each wave 32 q-rows; block covers 128 q-rows of one (b,h,c).
// Swapped QK^T (Pt = K*Q^T) so P->PV A-operand repacks in-register via cvt_pk+permlane32_swap.
__global__ __launch_bounds__(256) void attn_kernel(
    const float* __restrict__ q, const float* __restrict__ k,
    const unsigned short* __restrict__ vth,
    const float* __restrict__ beta, float* __restrict__ XT)
{
    const int bh = blockIdx.z; const int b = bh >> 4, h = bh & 15;
    const int c = blockIdx.y;
    const int qt = blockIdx.x;            // q-tile 0..3 (128 rows each)
    const int tid = threadIdx.x;
    const int lane = tid & 63;
    const int w = tid >> 6;
    const int lq = lane & 31;
    const int hi = lane >> 5;
    const float g = 1.f / (1.f + __expf(-beta[0]));

    __shared__ __align__(16) unsigned short Qs[128 * 64];  // bf16, swizzled rows of 128B
    __shared__ __align__(16) unsigned short Ks[64 * 64];   // bf16 [t][d]
    __shared__ __align__(16) unsigned short Vs[64 * 64];   // bf16 [d][t]
    __shared__ float lsum_lds[128];

    const size_t rowb = (size_t)b * Lz * Dz + (size_t)h * DHz;

    // ---- stage Q tile (128 rows) fp32 -> bf16, XOR-swizzled ----
    {
        const int r = tid >> 2, c4 = tid & 3;
#pragma unroll
        for (int p = 0; p < 2; ++p) {
            int rr = p * 64 + r;
            const float* qp = q + rowb + (size_t)(c * Sz + qt * 128 + rr) * Dz + c4 * 16;
            float4 f0 = ((const float4*)qp)[0];
            float4 f1 = ((const float4*)qp)[1];
            float4 f2 = ((const float4*)qp)[2];
            float4 f3 = ((const float4*)qp)[3];
            uint4 u0, u1;
            u0.x = pkbf(f0.x, f0.y); u0.y = pkbf(f0.z, f0.w);
            u0.z = pkbf(f1.x, f1.y); u0.w = pkbf(f1.z, f1.w);
            u1.x = pkbf(f2.x, f2.y); u1.y = pkbf(f2.z, f2.w);
            u1.z = pkbf(f3.x, f3.y); u1.w = pkbf(f3.z, f3.w);
            int base = rr * 128;
            *(uint4*)((char*)Qs + base + ((c4 * 32)      ^ ((rr & 7) << 4))) = u0;
            *(uint4*)((char*)Qs + base + ((c4 * 32 + 16) ^ ((rr & 7) << 4))) = u1;
        }
    }
    __syncthreads();
    // Q B-fragments: lane holds Q[q = w*32+lq][d = 8*hi + i + 16*ck]
    bf16x8 qf[4];
#pragma unroll
    for (int ck = 0; ck < 4; ++ck) {
        int rr = w * 32 + lq;
        qf[ck] = *(const bf16x8*)((const char*)Qs + rr * 128 + ((ck * 32 + hi * 16) ^ ((rr & 7) << 4)));
    }

    f32x16 acc0, acc1;
#pragma unroll
    for (int r = 0; r < 16; ++r) { acc0[r] = 0.f; acc1[r] = 0.f; }
    float lsum = 0.f;

    for (int kt = 0; kt < 8; ++kt) {
        __syncthreads();
        // ---- stage K (fp32->bf16, [t][d]) and V (bf16 from vth, [d][t]), swizzled ----
        {
            const int r = tid >> 2, c4 = tid & 3;
            const float* kp = k + rowb + (size_t)(c * Sz + kt * 64 + r) * Dz + c4 * 16;
            float4 f0 = ((const float4*)kp)[0];
            float4 f1 = ((const float4*)kp)[1];
            float4 f2 = ((const float4*)kp)[2];
            float4 f3 = ((const float4*)kp)[3];
            uint4 u0, u1;
            u0.x = pkbf(f0.x, f0.y); u0.y = pkbf(f0.z, f0.w);
            u0.z = pkbf(f1.x, f1.y); u0.w = pkbf(f1.z, f1.w);
            u1.x = pkbf(f2.x, f2.y); u1.y = pkbf(f2.z, f2.w);
            u1.z = pkbf(f3.x, f3.y); u1.w = pkbf(f3.z, f3.w);
            int base = r * 128;
            *(uint4*)((char*)Ks + base + ((c4 * 32)      ^ ((r & 7) << 4))) = u0;
            *(uint4*)((char*)Ks + base + ((c4 * 32 + 16) ^ ((r & 7) << 4))) = u1;
            // V: row index r is d, columns are t (already bf16 in vth)
            const unsigned short* vp = vth + ((size_t)(b * Hz + h) * 64 + r) * Lz + c * Sz + kt * 64 + c4 * 16;
            uint4 v0 = ((const uint4*)vp)[0];
            uint4 v1 = ((const uint4*)vp)[1];
            *(uint4*)((char*)Vs + base + ((c4 * 32)      ^ ((r & 7) << 4))) = v0;
            *(uint4*)((char*)Vs + base + ((c4 * 32 + 16) ^ ((r & 7) << 4))) = v1;
        }
        __syncthreads();

        bf16x8 pA[4];
#pragma unroll
        for (int tb = 0; tb < 2; ++tb) {
            f32x16 pt;
#pragma unroll
            for (int r = 0; r < 16; ++r) pt[r] = 0.f;
#pragma unroll
            for (int ck = 0; ck < 4; ++ck) {
                int rr = tb * 32 + lq;
                bf16x8 ka = *(const bf16x8*)((const char*)Ks + rr * 128 + ((ck * 32 + hi * 16) ^ ((rr & 7) << 4)));
                // Pt[t][q] += K[t][d] * Q[q][d]
                pt = __builtin_amdgcn_mfma_f32_32x32x16_bf16(ka, qf[ck], pt, 0, 0, 0);
            }
            // p = exp(logit*scale); lane covers t = tb*32 + (r&3)+8*(r>>2)+4*hi for q = w*32+lq
            float p[16];
#pragma unroll
            for (int r = 0; r < 16; ++r) { p[r] = __expf(pt[r] * 0.125f); lsum += p[r]; }
            // repack D-layout (col=q) -> A-layout (m=q, k=t) via cvt_pk + permlane32_swap
#pragma unroll
            for (int cc = 0; cc < 2; ++cc) {
                unsigned u0 = pkbf(p[8 * cc + 0], p[8 * cc + 1]);
                unsigned u1 = pkbf(p[8 * cc + 2], p[8 * cc + 3]);
                unsigned u2 = pkbf(p[8 * cc + 4], p[8 * cc + 5]);
                unsigned u3 = pkbf(p[8 * cc + 6], p[8 * cc + 7]);
                asm volatile("v_permlane32_swap_b32 %0, %1" : "+v"(u0), "+v"(u2));
                asm volatile("v_permlane32_swap_b32 %0, %1" : "+v"(u1), "+v"(u3));
                union { unsigned u[4]; bf16x8 v; } pa;
                pa.u[0] = u0; pa.u[1] = u1; pa.u[2] = u2; pa.u[3] = u3;
                pA[tb * 2 + cc] = pa.v;
            }
        }
        // PV: out[q][d] += P[q][t] * V[t][d];  B-frag: lane holds V[t=8*hi+i+16*ck][d=nb*32+lq]
#pragma unroll
        for (int ck = 0; ck < 4; ++ck) {
            int r0 = lq;
            bf16x8 vf0 = *(const bf16x8*)((const char*)Vs + r0 * 128 + ((ck * 32 + hi * 16) ^ ((r0 & 7) << 4)));
            acc0 = __builtin_amdgcn_mfma_f32_32x32x16_bf16(pA[ck], vf0, acc0, 0, 0, 0);
            int r1 = 32 + lq;
            bf16x8 vf1 = *(const bf16x8*)((const char*)Vs + r1 * 128 + ((ck * 32 + hi * 16) ^ ((r1 & 7) << 4)));
            acc1 = __builtin_amdgcn_mfma_f32_32x32x16_bf16(pA[ck], vf1, acc1, 0, 0, 0);
        }
    }

    // finish row sums: lane and lane^32 each hold half the t's of row q=w*32+lq
    lsum += __shfl_xor(lsum, 32);
    if (hi == 0) lsum_lds[w * 32 + lq] = lsum;
    __syncthreads();

    const float invg = 1.f - g;
#pragma unroll
    for (int r = 0; r < 16; ++r) {
        int ql = (r & 3) + 8 * (r >> 2) + 4 * hi;
        float sc = invg / lsum_lds[w * 32 + ql];
        int s = qt * 128 + w * 32 + ql;
        int e = c * 128 + h * 8 + (s >> 6);
        float* xp = XT + ((size_t)b * Dz + e) * Lz + (s & 63) * 64;
        xp[lq]      = acc0[r] * sc;
        xp[32 + lq] = acc1[r] * sc;
    }
}

// ---------------- Scan phase 1: evolve M,z; store per-segment prefixes ----
// grid: 256 blocks = bh(64) x esplit(4); block 256 threads.
__global__ __launch_bounds__(256) void scan_s1(
    const float* __restrict__ k, const float* __restrict__ v,
    float* __restrict__ Mpre, float* __restrict__ zpre)
{
    const int bx = blockIdx.x;
    const int bh = bx >> 2, es = bx & 3;
    const int b = bh >> 4, h = bh & 15;
    const int tid = threadIdx.x;
    const int el = tid & 15;          // e-local 0..15
    const int rs = tid >> 4;          // 0..15
    const int eg = es * 16 + el;      // e within head, 0..63

    __shared__ float ks[64][68];      // sigma(k) rows, padded (+4) -> conflict-free
    __shared__ float vs2[64][16];     // v slice, later holds val, later mdelta exchange

    float Mreg[64];                   // column eg of M
#pragma unroll
    for (int d = 0; d < 64; ++d) Mreg[d] = 0.f;
    float zreg = 0.f;

    const size_t boff = (size_t)b * Lz * Dz + h * DHz;

    for (int c = 0; c < Cz; ++c) {
        // store prefix (pre-segment M, z) for S2
        {
            float* mp = Mpre + ((size_t)(bh * Cz + c) * 64) * 64;
#pragma unroll
            for (int j = 0; j < 4; ++j) {
                int d = rs * 4 + j;
                mp[(size_t)d * 64 + eg] = Mreg[d];
            }
            if (rs == 0) zpre[(size_t)(bh * Cz + c) * 64 + eg] = zreg;
        }
        float mdelta[4] = {0.f, 0.f, 0.f, 0.f};
        float zd = 0.f;

        for (int ch = 0; ch < 8; ++ch) {
            const int s0 = c * Sz + ch * 64;
            __syncthreads();
            // stage sigma(k): 64 rows x 64 d
#pragma unroll
            for (int it = 0; it < 4; ++it) {
                int idx = it * 256 + tid;
                int r = idx >> 4, f = (idx & 15) * 4;
                float4 t = *(const float4*)(k + boff + (size_t)(s0 + r) * Dz + f);
                ks[r][f + 0] = sigmaf(t.x); ks[r][f + 1] = sigmaf(t.y);
                ks[r][f + 2] = sigmaf(t.z); ks[r][f + 3] = sigmaf(t.w);
            }
            // stage v slice: 64 rows x 16 cols (this block's e-range)
            {
                int r = tid >> 2, f = (tid & 3) * 4;
                float4 t = *(const float4*)(v + boff + (size_t)(s0 + r) * Dz + es * 16 + f);
                *(float4*)&vs2[r][f] = t;
            }
            __syncthreads();
            // val = v - (sigma(k)@M)/(ssk*z+eps), each thread owns (sl=rs*4+j, el)
#pragma unroll
            for (int j = 0; j < 4; ++j) {
                const int sl = rs * 4 + j;
                float numk = 0.f, ssk = 0.f;
#pragma unroll
                for (int d = 0; d < 64; d += 4) {
                    float4 kk = *(const float4*)&ks[sl][d];
                    numk += kk.x * Mreg[d] + kk.y * Mreg[d + 1]
                          + kk.z * Mreg[d + 2] + kk.w * Mreg[d + 3];
                    ssk += kk.x + kk.y + kk.z + kk.w;
                }
                vs2[sl][el] = vs2[sl][el] - numk / (ssk * zreg + 1e-6f);
            }
            __syncthreads();
            // mdelta[d=rs*4+j][eg] += sum_sl sigma(k)[sl][d]*val[sl][eg]; also z delta
            for (int sl = 0; sl < 64; ++sl) {
                float vv = vs2[sl][el];
                float4 kk = *(const float4*)&ks[sl][rs * 4];
                mdelta[0] += kk.x * vv; mdelta[1] += kk.y * vv;
                mdelta[2] += kk.z * vv; mdelta[3] += kk.w * vv;
                zd += ks[sl][eg];
            }
        }
        // apply deltas: exchange mdelta columns via vs2
        __syncthreads();
#pragma unroll
        for (int j = 0; j < 4; ++j) vs2[rs * 4 + j][el] = mdelta[j];
        __syncthreads();
#pragma unroll
        for (int d = 0; d < 64; ++d) Mreg[d] += vs2[d][el];
        zreg += zd;
    }
}

// ---------------- Scan phase 2: A-readout from prefixes; XT += g*A ----
__global__ __launch_bounds__(256) void scan_s2(
    const float* __restrict__ q, const float* __restrict__ Mpre,
    const float* __restrict__ zpre, const float* __restrict__ beta,
    float* __restrict__ XT)
{
    const int bh = blockIdx.z; const int b = bh >> 4, h = bh & 15;
    const int c = blockIdx.y;
    const int tile = blockIdx.x;          // 0..7
    const int tid = threadIdx.x;
    const int lane = tid & 63;            // e
    const int w = tid >> 6;               // wave 0..3
    const float g = 1.f / (1.f + __expf(-beta[0]));

    __shared__ float qs[64][68];

    float Mreg[64];
    const float* mp = Mpre + ((size_t)(bh * Cz + c) * 64) * 64;
#pragma unroll
    for (int d = 0; d < 64; ++d) Mreg[d] = mp[(size_t)d * 64 + lane];
    const float zv = zpre[(size_t)(bh * Cz + c) * 64 + lane];

    const size_t boff = (size_t)b * Lz * Dz + h * DHz;
    const int s0 = c * Sz + tile * 64;
#pragma unroll
    for (int it = 0; it < 4; ++it) {
        int idx = it * 256 + tid;
        int r = idx >> 4, f = (idx & 15) * 4;
        float4 t = *(const float4*)(q + boff + (size_t)(s0 + r) * Dz + f);
        qs[r][f + 0] = sigmaf(t.x); qs[r][f + 1] = sigmaf(t.y);
        qs[r][f + 2] = sigmaf(t.z); qs[r][f + 3] = sigmaf(t.w);
    }
    __syncthreads();

    const int e_out = c * 128 + h * 8 + tile;
    float* xp = XT + ((size_t)b * Dz + e_out) * Lz;
    for (int i = 0; i < 16; ++i) {
        const int sl = w * 16 + i;
        float num = 0.f, ssq = 0.f;
#pragma unroll
        for (int d = 0; d < 64; d += 4) {
            float4 qq = *(const float4*)&qs[sl][d];
            num += qq.x * Mreg[d] + qq.y * Mreg[d + 1]
                 + qq.z * Mreg[d + 2] + qq.w * Mreg[d + 3];
            ssq += qq.x + qq.y + qq.z + qq.w;
        }
        float A = num / (ssq * zv + 1e-6f);
        size_t xoff = (size_t)sl * 64 + lane;
        xp[xoff] += g * A;
    }
}

// ---------------- Output GEMM: out[b,l,n] = sum_e XT[b,e,l]*Wo[e,n] + bo[n] ----
__global__ __launch_bounds__(256) void out_gemm(
    const float* __restrict__ XT, const float* __restrict__ Wo,
    const float* __restrict__ bo, float* __restrict__ out)
{
    const int b = blockIdx.z;
    const int n0 = blockIdx.x * 64;
    const int l0 = blockIdx.y * 64;
    __shared__ float As[16][64];   // [e][l]
    __shared__ float Bs[16][64];   // [e][n]
    const int tid = threadIdx.x;
    const int tx = tid & 15, ty = tid >> 4;
    float acc[4][4] = {{0.f}};
    const int ar = tid >> 4;
    const int ac = (tid & 15) * 4;
    const float* Xb = XT + (size_t)b * Dz * Lz;

    for (int k0 = 0; k0 < Dz; k0 += 16) {
        float4 a  = *(const float4*)&Xb[(size_t)(k0 + ar) * Lz + l0 + ac];
        float4 b4 = *(const float4*)&Wo[(size_t)(k0 + ar) * Dz + n0 + ac];
        __syncthreads();
        *(float4*)&As[ar][ac] = a;
        *(float4*)&Bs[ar][ac] = b4;
        __syncthreads();
#pragma unroll
        for (int kk = 0; kk < 16; ++kk) {
            float av[4], bv4[4];
            *(float4*)av  = *(const float4*)&As[kk][ty * 4];
            *(float4*)bv4 = *(const float4*)&Bs[kk][tx * 4];
#pragma unroll
            for (int i = 0; i < 4; ++i)
#pragma unroll
                for (int j = 0; j < 4; ++j) acc[i][j] += av[i] * bv4[j];
        }
    }
#pragma unroll
    for (int i = 0; i < 4; ++i) {
        int l = l0 + ty * 4 + i;
        float4 o;
        o.x = acc[i][0] + bo[n0 + tx * 4 + 0];
        o.y = acc[i][1] + bo[n0 + tx * 4 + 1];
        o.z = acc[i][2] + bo[n0 + tx * 4 + 2];
        o.w = acc[i][3] + bo[n0 + tx * 4 + 3];
        *(float4*)&out[((size_t)b * Lz + l) * Dz + n0 + tx * 4] = o;
    }
}

extern "C" void kernel_launch(void* const* d_in, const int* in_sizes, int n_in,
                              void* d_out, int out_size, void* d_ws, size_t ws_size,
                              hipStream_t stream)
{
    (void)in_sizes; (void)n_in; (void)out_size; (void)ws_size;
    const float* query  = (const float*)d_in[0];
    const float* key_in = (const float*)d_in[1];
    const float* value  = (const float*)d_in[2];
    const float* Wq = (const float*)d_in[3];
    const float* bq = (const float*)d_in[4];
    const float* Wk = (const float*)d_in[5];
    const float* bk = (const float*)d_in[6];
    const float* Wv = (const float*)d_in[7];
    const float* bv = (const float*)d_in[8];
    const float* Wo = (const float*)d_in[9];
    const float* bo = (const float*)d_in[10];
    const float* beta = (const float*)d_in[11];
    float* out = (float*)d_out;

    const size_t NE = (size_t)Bz * Lz * Dz;            // 16,777,216 per buffer
    const size_t NM = (size_t)64 * Cz * 64 * 64;       // M prefixes
    float* qb = (float*)d_ws;
    float* kb = qb + NE;
    float* vb = kb + NE;
    float* Mpre = vb + NE;
    float* zpre = Mpre + NM;
    // vb doubles as XT after scan_s1 has consumed v; vth (bf16 V^T) lives in d_out
    // until out_gemm overwrites it at the end. Required ws = 3*NE + NM + NZ (same
    // minimum the previous kernel already dereferenced).
    float* XT = vb;
    unsigned short* vth = (unsigned short*)d_out;

    proj_kernel<<<dim3(16, 256, 3), 256, 0, stream>>>(query, key_in, value,
                                                      Wq, bq, Wk, bk, Wv, bv, qb, kb, vb);
    vt_kernel<<<dim3(Lz / 64, Hz, Bz), 256, 0, stream>>>(vb, vth);
    scan_s1<<<dim3(256), 256, 0, stream>>>(kb, vb, Mpre, zpre);
    attn_kernel<<<dim3(4, Cz, Bz * Hz), 256, 0, stream>>>(qb, kb, vth, beta, XT);
    scan_s2<<<dim3(8, Cz, Bz * Hz), 256, 0, stream>>>(qb, Mpre, zpre, beta, XT);
    out_gemm<<<dim3(16, 64, Bz), 256, 0, stream>>>(XT, Wo, bo, out);
}

// Round 3
// 1915.132 us; speedup vs baseline: 2.0332x; 1.4408x over previous
//
#include <hip/hip_runtime.h>
#include <math.h>

#define Bz 4
#define Lz 4096
#define Dz 1024
#define Hz 16
#define Cz 8
#define Sz 512
#define DHz 64

typedef __bf16 bf16x8 __attribute__((ext_vector_type(8)));
typedef float f32x16 __attribute__((ext_vector_type(16)));

__device__ __forceinline__ float sigmaf(float x) {
    return x >= 0.f ? x : expm1f(x);
}

// pack two f32 -> one dword of 2 bf16 (RNE), lo = a, hi = b
__device__ __forceinline__ unsigned pkbf(float a, float b) {
    unsigned r;
    asm("v_cvt_pk_bf16_f32 %0, %1, %2" : "=v"(r) : "v"(a), "v"(b));
    return r;
}

// ---------------- W transpose+split: dst[n][k] (hi plane, then lo plane) <- W[k][n]
__global__ __launch_bounds__(256) void wt_kernel(
    const float* __restrict__ W, unsigned short* __restrict__ dst)
{
    __shared__ float Ls[64][65];
    const int tid = threadIdx.x;
    const int n0 = blockIdx.x * 64, k0 = blockIdx.y * 64;
#pragma unroll
    for (int i = 0; i < 4; ++i) {
        int idx = i * 256 + tid;
        int r = idx >> 4, c4 = (idx & 15) * 4;
        float4 t = *(const float4*)&W[(size_t)(k0 + r) * 1024 + n0 + c4];
        Ls[r][c4] = t.x; Ls[r][c4 + 1] = t.y; Ls[r][c4 + 2] = t.z; Ls[r][c4 + 3] = t.w;
    }
    __syncthreads();
    const int n = tid >> 2, j0 = (tid & 3) * 16;
    unsigned uh[8], ul[8];
#pragma unroll
    for (int j = 0; j < 8; ++j) {
        float a = Ls[j0 + 2 * j][n], b = Ls[j0 + 2 * j + 1][n];
        unsigned h = pkbf(a, b);
        float ra = a - __uint_as_float(h << 16);
        float rb = b - __uint_as_float(h & 0xffff0000u);
        uh[j] = h; ul[j] = pkbf(ra, rb);
    }
    unsigned short* op = dst + (size_t)(n0 + n) * 1024 + k0 + j0;
    uint4 o;
    o.x = uh[0]; o.y = uh[1]; o.z = uh[2]; o.w = uh[3]; *(uint4*)op = o;
    o.x = uh[4]; o.y = uh[5]; o.z = uh[6]; o.w = uh[7]; *(uint4*)(op + 8) = o;
    op += 1048576;
    o.x = ul[0]; o.y = ul[1]; o.z = ul[2]; o.w = ul[3]; *(uint4*)op = o;
    o.x = ul[4]; o.y = ul[5]; o.z = ul[6]; o.w = ul[7]; *(uint4*)(op + 8) = o;
}

// ---------------- XT transpose+split: dst[(b*L+l)][e] (hi, lo planes) <- XT[b][e][l]
__global__ __launch_bounds__(256) void xtt_kernel(
    const float* __restrict__ XT, unsigned short* __restrict__ dst)
{
    __shared__ float Ls[64][65];
    const int tid = threadIdx.x;
    const int b = blockIdx.z, e0 = blockIdx.y * 64, l0 = blockIdx.x * 64;
#pragma unroll
    for (int i = 0; i < 4; ++i) {
        int idx = i * 256 + tid;
        int r = idx >> 4, c4 = (idx & 15) * 4;
        float4 t = *(const float4*)&XT[((size_t)b * 1024 + e0 + r) * 4096 + l0 + c4];
        Ls[r][c4] = t.x; Ls[r][c4 + 1] = t.y; Ls[r][c4 + 2] = t.z; Ls[r][c4 + 3] = t.w;
    }
    __syncthreads();
    const int l = tid >> 2, j0 = (tid & 3) * 16;
    unsigned uh[8], ul[8];
#pragma unroll
    for (int j = 0; j < 8; ++j) {
        float a = Ls[j0 + 2 * j][l], b2 = Ls[j0 + 2 * j + 1][l];
        unsigned h = pkbf(a, b2);
        float ra = a - __uint_as_float(h << 16);
        float rb = b2 - __uint_as_float(h & 0xffff0000u);
        uh[j] = h; ul[j] = pkbf(ra, rb);
    }
    unsigned short* op = dst + ((size_t)(b * 4096 + l0 + l)) * 1024 + e0 + j0;
    uint4 o;
    o.x = uh[0]; o.y = uh[1]; o.z = uh[2]; o.w = uh[3]; *(uint4*)op = o;
    o.x = uh[4]; o.y = uh[5]; o.z = uh[6]; o.w = uh[7]; *(uint4*)(op + 8) = o;
    op += 16777216;
    o.x = ul[0]; o.y = ul[1]; o.z = ul[2]; o.w = ul[3]; *(uint4*)op = o;
    o.x = ul[4]; o.y = ul[5]; o.z = ul[6]; o.w = ul[7]; *(uint4*)(op + 8) = o;
}

// ---------------- Split-bf16 MFMA GEMM: C[m][n] = sum_k A[m][k]*Bt[n][k] + bias[n]
// M=16384, K=N=1024. Bt pre-split bf16 planes [2][1024][1024] (n-major, k contig).
// ASPLIT: A is fp32, split hi/lo on the fly; else A is pre-split planes [2][16384][1024].
// FULL4: include Al*Bl (full fp32-class, rel err ~2^-24); else 3 terms (~2^-16).
template<bool ASPLIT, bool FULL4>
__global__ __launch_bounds__(256) void mm_split(
    const float* __restrict__ Af32, const unsigned short* __restrict__ Abf,
    const unsigned short* __restrict__ Bt,
    const float* __restrict__ bias, float* __restrict__ C)
{
    __shared__ __align__(16) unsigned short Ah[128 * 64];
    __shared__ __align__(16) unsigned short Al[128 * 64];
    __shared__ __align__(16) unsigned short Bh[128 * 64];
    __shared__ __align__(16) unsigned short Bl[128 * 64];
    const int tid = threadIdx.x;
    const int m0 = blockIdx.y * 128, n0 = blockIdx.x * 128;
    const int lane = tid & 63, w = tid >> 6;
    const int lq = lane & 31, hi = lane >> 5;
    const int wm = (w >> 1) * 64, wn = (w & 1) * 64;

    f32x16 acc[2][2];
#pragma unroll
    for (int i = 0; i < 2; ++i)
#pragma unroll
        for (int j = 0; j < 2; ++j)
#pragma unroll
            for (int r = 0; r < 16; ++r) acc[i][j][r] = 0.f;

    for (int kb = 0; kb < 1024; kb += 64) {
        __syncthreads();
        if constexpr (ASPLIT) {
#pragma unroll
            for (int i = 0; i < 8; ++i) {
                int idx = i * 256 + tid;
                int r = idx >> 4, fq = idx & 15;
                float4 a = *(const float4*)(Af32 + (size_t)(m0 + r) * 1024 + kb + fq * 4);
                unsigned h0 = pkbf(a.x, a.y), h1 = pkbf(a.z, a.w);
                float rx = a.x - __uint_as_float(h0 << 16);
                float ry = a.y - __uint_as_float(h0 & 0xffff0000u);
                float rz = a.z - __uint_as_float(h1 << 16);
                float rw = a.w - __uint_as_float(h1 & 0xffff0000u);
                unsigned l0 = pkbf(rx, ry), l1 = pkbf(rz, rw);
                int boff = r * 128 + ((fq * 8) ^ ((r & 7) << 4));
                uint2 th; th.x = h0; th.y = h1;
                uint2 tl; tl.x = l0; tl.y = l1;
                *(uint2*)((char*)Ah + boff) = th;
                *(uint2*)((char*)Al + boff) = tl;
            }
        } else {
#pragma unroll
            for (int p = 0; p < 2; ++p) {
                const unsigned short* ap = Abf + (size_t)p * 16777216 + (size_t)m0 * 1024 + kb;
                unsigned short* dst = p ? Al : Ah;
#pragma unroll
                for (int i = 0; i < 4; ++i) {
                    int idx = i * 256 + tid;
                    int r = idx >> 3, uq = idx & 7;
                    uint4 d = *(const uint4*)(ap + (size_t)r * 1024 + uq * 8);
                    *(uint4*)((char*)dst + r * 128 + ((uq * 16) ^ ((r & 7) << 4))) = d;
                }
            }
        }
#pragma unroll
        for (int p = 0; p < 2; ++p) {
            const unsigned short* bp = Bt + (size_t)p * 1048576 + (size_t)n0 * 1024 + kb;
            unsigned short* dst = p ? Bl : Bh;
#pragma unroll
            for (int i = 0; i < 4; ++i) {
                int idx = i * 256 + tid;
                int r = idx >> 3, uq = idx & 7;
                uint4 d = *(const uint4*)(bp + (size_t)r * 1024 + uq * 8);
                *(uint4*)((char*)dst + r * 128 + ((uq * 16) ^ ((r & 7) << 4))) = d;
            }
        }
        __syncthreads();
#pragma unroll
        for (int kt = 0; kt < 4; ++kt) {
            bf16x8 fah[2], fal[2], fbh[2], fbl[2];
            const int cb = kt * 32 + hi * 16;
#pragma unroll
            for (int mb = 0; mb < 2; ++mb) {
                int r = wm + mb * 32 + lq;
                int off = r * 128 + (cb ^ ((r & 7) << 4));
                fah[mb] = *(const bf16x8*)((const char*)Ah + off);
                fal[mb] = *(const bf16x8*)((const char*)Al + off);
            }
#pragma unroll
            for (int nb = 0; nb < 2; ++nb) {
                int r = wn + nb * 32 + lq;
                int off = r * 128 + (cb ^ ((r & 7) << 4));
                fbh[nb] = *(const bf16x8*)((const char*)Bh + off);
                fbl[nb] = *(const bf16x8*)((const char*)Bl + off);
            }
#pragma unroll
            for (int mb = 0; mb < 2; ++mb)
#pragma unroll
                for (int nb = 0; nb < 2; ++nb) {
                    acc[mb][nb] = __builtin_amdgcn_mfma_f32_32x32x16_bf16(fah[mb], fbh[nb], acc[mb][nb], 0, 0, 0);
                    acc[mb][nb] = __builtin_amdgcn_mfma_f32_32x32x16_bf16(fah[mb], fbl[nb], acc[mb][nb], 0, 0, 0);
                    acc[mb][nb] = __builtin_amdgcn_mfma_f32_32x32x16_bf16(fal[mb], fbh[nb], acc[mb][nb], 0, 0, 0);
                    if constexpr (FULL4)
                        acc[mb][nb] = __builtin_amdgcn_mfma_f32_32x32x16_bf16(fal[mb], fbl[nb], acc[mb][nb], 0, 0, 0);
                }
        }
    }
#pragma unroll
    for (int mb = 0; mb < 2; ++mb)
#pragma unroll
        for (int nb = 0; nb < 2; ++nb) {
            int n = n0 + wn + nb * 32 + lq;
            float bn = bias[n];
#pragma unroll
            for (int r = 0; r < 16; ++r) {
                int m = m0 + wm + mb * 32 + (r & 3) + 8 * (r >> 2) + 4 * hi;
                C[(size_t)m * 1024 + n] = acc[mb][nb][r] + bn;
            }
        }
}

// ---------------- V transpose to bf16: vth[b][h][d][L] <- v[b][l][h*64+d] ----
__global__ __launch_bounds__(256) void vt_kernel(
    const float* __restrict__ v, unsigned short* __restrict__ vth)
{
    const int b = blockIdx.z, h = blockIdx.y, l0 = blockIdx.x * 64;
    const int tid = threadIdx.x;
    __shared__ float Ls[64][65];
#pragma unroll
    for (int it = 0; it < 4; ++it) {
        int idx = it * 256 + tid;
        int r = idx >> 4, c4 = (idx & 15) * 4;
        float4 t = *(const float4*)&v[((size_t)b * Lz + l0 + r) * Dz + h * DHz + c4];
        Ls[r][c4] = t.x; Ls[r][c4 + 1] = t.y; Ls[r][c4 + 2] = t.z; Ls[r][c4 + 3] = t.w;
    }
    __syncthreads();
    const int d = tid >> 2, j0 = (tid & 3) * 16;
    unsigned u[8];
#pragma unroll
    for (int j = 0; j < 8; ++j)
        u[j] = pkbf(Ls[j0 + 2 * j][d], Ls[j0 + 2 * j + 1][d]);
    unsigned short* op = vth + ((size_t)(b * Hz + h) * 64 + d) * Lz + l0 + j0;
    uint4 o0; o0.x = u[0]; o0.y = u[1]; o0.z = u[2]; o0.w = u[3];
    uint4 o1; o1.x = u[4]; o1.y = u[5]; o1.z = u[6]; o1.w = u[7];
    *(uint4*)op = o0;
    *(uint4*)(op + 8) = o1;
}

// ---------------- MFMA local attention; writes (1-g)*dot into XT[b][e][l] ----
__global__ __launch_bounds__(256) void attn_kernel(
    const float* __restrict__ q, const float* __restrict__ k,
    const unsigned short* __restrict__ vth,
    const float* __restrict__ beta, float* __restrict__ XT)
{
    const int bh = blockIdx.z; const int b = bh >> 4, h = bh & 15;
    const int c = blockIdx.y;
    const int qt = blockIdx.x;            // q-tile 0..3 (128 rows each)
    const int tid = threadIdx.x;
    const int lane = tid & 63;
    const int w = tid >> 6;
    const int lq = lane & 31;
    const int hi = lane >> 5;
    const float g = 1.f / (1.f + __expf(-beta[0]));

    __shared__ __align__(16) unsigned short Qs[128 * 64];  // bf16, swizzled rows of 128B
    __shared__ __align__(16) unsigned short Ks[64 * 64];   // bf16 [t][d]
    __shared__ __align__(16) unsigned short Vs[64 * 64];   // bf16 [d][t]
    __shared__ float lsum_lds[128];

    const size_t rowb = (size_t)b * Lz * Dz + (size_t)h * DHz;

    // ---- stage Q tile (128 rows) fp32 -> bf16, XOR-swizzled ----
    {
        const int r = tid >> 2, c4 = tid & 3;
#pragma unroll
        for (int p = 0; p < 2; ++p) {
            int rr = p * 64 + r;
            const float* qp = q + rowb + (size_t)(c * Sz + qt * 128 + rr) * Dz + c4 * 16;
            float4 f0 = ((const float4*)qp)[0];
            float4 f1 = ((const float4*)qp)[1];
            float4 f2 = ((const float4*)qp)[2];
            float4 f3 = ((const float4*)qp)[3];
            uint4 u0, u1;
            u0.x = pkbf(f0.x, f0.y); u0.y = pkbf(f0.z, f0.w);
            u0.z = pkbf(f1.x, f1.y); u0.w = pkbf(f1.z, f1.w);
            u1.x = pkbf(f2.x, f2.y); u1.y = pkbf(f2.z, f2.w);
            u1.z = pkbf(f3.x, f3.y); u1.w = pkbf(f3.z, f3.w);
            int base = rr * 128;
            *(uint4*)((char*)Qs + base + ((c4 * 32)      ^ ((rr & 7) << 4))) = u0;
            *(uint4*)((char*)Qs + base + ((c4 * 32 + 16) ^ ((rr & 7) << 4))) = u1;
        }
    }
    __syncthreads();
    // Q B-fragments: lane holds Q[q = w*32+lq][d = 8*hi + i + 16*ck]
    bf16x8 qf[4];
#pragma unroll
    for (int ck = 0; ck < 4; ++ck) {
        int rr = w * 32 + lq;
        qf[ck] = *(const bf16x8*)((const char*)Qs + rr * 128 + ((ck * 32 + hi * 16) ^ ((rr & 7) << 4)));
    }

    f32x16 acc0, acc1;
#pragma unroll
    for (int r = 0; r < 16; ++r) { acc0[r] = 0.f; acc1[r] = 0.f; }
    float lsum = 0.f;

    for (int kt = 0; kt < 8; ++kt) {
        __syncthreads();
        // ---- stage K (fp32->bf16, [t][d]) and V (bf16 from vth, [d][t]), swizzled ----
        {
            const int r = tid >> 2, c4 = tid & 3;
            const float* kp = k + rowb + (size_t)(c * Sz + kt * 64 + r) * Dz + c4 * 16;
            float4 f0 = ((const float4*)kp)[0];
            float4 f1 = ((const float4*)kp)[1];
            float4 f2 = ((const float4*)kp)[2];
            float4 f3 = ((const float4*)kp)[3];
            uint4 u0, u1;
            u0.x = pkbf(f0.x, f0.y); u0.y = pkbf(f0.z, f0.w);
            u0.z = pkbf(f1.x, f1.y); u0.w = pkbf(f1.z, f1.w);
            u1.x = pkbf(f2.x, f2.y); u1.y = pkbf(f2.z, f2.w);
            u1.z = pkbf(f3.x, f3.y); u1.w = pkbf(f3.z, f3.w);
            int base = r * 128;
            *(uint4*)((char*)Ks + base + ((c4 * 32)      ^ ((r & 7) << 4))) = u0;
            *(uint4*)((char*)Ks + base + ((c4 * 32 + 16) ^ ((r & 7) << 4))) = u1;
            // V: row index r is d, columns are t (already bf16 in vth)
            const unsigned short* vp = vth + ((size_t)(b * Hz + h) * 64 + r) * Lz + c * Sz + kt * 64 + c4 * 16;
            uint4 v0 = ((const uint4*)vp)[0];
            uint4 v1 = ((const uint4*)vp)[1];
            *(uint4*)((char*)Vs + base + ((c4 * 32)      ^ ((r & 7) << 4))) = v0;
            *(uint4*)((char*)Vs + base + ((c4 * 32 + 16) ^ ((r & 7) << 4))) = v1;
        }
        __syncthreads();

        bf16x8 pA[4];
#pragma unroll
        for (int tb = 0; tb < 2; ++tb) {
            f32x16 pt;
#pragma unroll
            for (int r = 0; r < 16; ++r) pt[r] = 0.f;
#pragma unroll
            for (int ck = 0; ck < 4; ++ck) {
                int rr = tb * 32 + lq;
                bf16x8 ka = *(const bf16x8*)((const char*)Ks + rr * 128 + ((ck * 32 + hi * 16) ^ ((rr & 7) << 4)));
                // Pt[t][q] += K[t][d] * Q[q][d]
                pt = __builtin_amdgcn_mfma_f32_32x32x16_bf16(ka, qf[ck], pt, 0, 0, 0);
            }
            // p = exp(logit*scale); lane covers t = tb*32 + (r&3)+8*(r>>2)+4*hi for q = w*32+lq
            float p[16];
#pragma unroll
            for (int r = 0; r < 16; ++r) { p[r] = __expf(pt[r] * 0.125f); lsum += p[r]; }
            // repack D-layout (col=q) -> A-layout (m=q, k=t) via cvt_pk + permlane32_swap
#pragma unroll
            for (int cc = 0; cc < 2; ++cc) {
                unsigned u0 = pkbf(p[8 * cc + 0], p[8 * cc + 1]);
                unsigned u1 = pkbf(p[8 * cc + 2], p[8 * cc + 3]);
                unsigned u2 = pkbf(p[8 * cc + 4], p[8 * cc + 5]);
                unsigned u3 = pkbf(p[8 * cc + 6], p[8 * cc + 7]);
                asm volatile("v_permlane32_swap_b32 %0, %1" : "+v"(u0), "+v"(u2));
                asm volatile("v_permlane32_swap_b32 %0, %1" : "+v"(u1), "+v"(u3));
                union { unsigned u[4]; bf16x8 v; } pa;
                pa.u[0] = u0; pa.u[1] = u1; pa.u[2] = u2; pa.u[3] = u3;
                pA[tb * 2 + cc] = pa.v;
            }
        }
        // PV: out[q][d] += P[q][t] * V[t][d]
#pragma unroll
        for (int ck = 0; ck < 4; ++ck) {
            int r0 = lq;
            bf16x8 vf0 = *(const bf16x8*)((const char*)Vs + r0 * 128 + ((ck * 32 + hi * 16) ^ ((r0 & 7) << 4)));
            acc0 = __builtin_amdgcn_mfma_f32_32x32x16_bf16(pA[ck], vf0, acc0, 0, 0, 0);
            int r1 = 32 + lq;
            bf16x8 vf1 = *(const bf16x8*)((const char*)Vs + r1 * 128 + ((ck * 32 + hi * 16) ^ ((r1 & 7) << 4)));
            acc1 = __builtin_amdgcn_mfma_f32_32x32x16_bf16(pA[ck], vf1, acc1, 0, 0, 0);
        }
    }

    // finish row sums: lane and lane^32 each hold half the t's of row q=w*32+lq
    lsum += __shfl_xor(lsum, 32);
    if (hi == 0) lsum_lds[w * 32 + lq] = lsum;
    __syncthreads();

    const float invg = 1.f - g;
#pragma unroll
    for (int r = 0; r < 16; ++r) {
        int ql = (r & 3) + 8 * (r >> 2) + 4 * hi;
        float sc = invg / lsum_lds[w * 32 + ql];
        int s = qt * 128 + w * 32 + ql;
        int e = c * 128 + h * 8 + (s >> 6);
        float* xp = XT + ((size_t)b * Dz + e) * Lz + (s & 63) * 64;
        xp[lq]      = acc0[r] * sc;
        xp[32 + lq] = acc1[r] * sc;
    }
}

// ---------------- Scan phase 1: evolve M,z; store per-segment prefixes ----
__global__ __launch_bounds__(256) void scan_s1(
    const float* __restrict__ k, const float* __restrict__ v,
    float* __restrict__ Mpre, float* __restrict__ zpre)
{
    const int bx = blockIdx.x;
    const int bh = bx >> 2, es = bx & 3;
    const int b = bh >> 4, h = bh & 15;
    const int tid = threadIdx.x;
    const int el = tid & 15;          // e-local 0..15
    const int rs = tid >> 4;          // 0..15
    const int eg = es * 16 + el;      // e within head, 0..63

    __shared__ float ks[64][68];      // sigma(k) rows, padded (+4) -> conflict-free
    __shared__ float vs2[64][16];     // v slice, later holds val, later mdelta exchange

    float Mreg[64];                   // column eg of M
#pragma unroll
    for (int d = 0; d < 64; ++d) Mreg[d] = 0.f;
    float zreg = 0.f;

    const size_t boff = (size_t)b * Lz * Dz + h * DHz;

    for (int c = 0; c < Cz; ++c) {
        {
            float* mp = Mpre + ((size_t)(bh * Cz + c) * 64) * 64;
#pragma unroll
            for (int j = 0; j < 4; ++j) {
                int d = rs * 4 + j;
                mp[(size_t)d * 64 + eg] = Mreg[d];
            }
            if (rs == 0) zpre[(size_t)(bh * Cz + c) * 64 + eg] = zreg;
        }
        float mdelta[4] = {0.f, 0.f, 0.f, 0.f};
        float zd = 0.f;

        for (int ch = 0; ch < 8; ++ch) {
            const int s0 = c * Sz + ch * 64;
            __syncthreads();
#pragma unroll
            for (int it = 0; it < 4; ++it) {
                int idx = it * 256 + tid;
                int r = idx >> 4, f = (idx & 15) * 4;
                float4 t = *(const float4*)(k + boff + (size_t)(s0 + r) * Dz + f);
                ks[r][f + 0] = sigmaf(t.x); ks[r][f + 1] = sigmaf(t.y);
                ks[r][f + 2] = sigmaf(t.z); ks[r][f + 3] = sigmaf(t.w);
            }
            {
                int r = tid >> 2, f = (tid & 3) * 4;
                float4 t = *(const float4*)(v + boff + (size_t)(s0 + r) * Dz + es * 16 + f);
                *(float4*)&vs2[r][f] = t;
            }
            __syncthreads();
#pragma unroll
            for (int j = 0; j < 4; ++j) {
                const int sl = rs * 4 + j;
                float numk = 0.f, ssk = 0.f;
#pragma unroll
                for (int d = 0; d < 64; d += 4) {
                    float4 kk = *(const float4*)&ks[sl][d];
                    numk += kk.x * Mreg[d] + kk.y * Mreg[d + 1]
                          + kk.z * Mreg[d + 2] + kk.w * Mreg[d + 3];
                    ssk += kk.x + kk.y + kk.z + kk.w;
                }
                vs2[sl][el] = vs2[sl][el] - numk / (ssk * zreg + 1e-6f);
            }
            __syncthreads();
            for (int sl = 0; sl < 64; ++sl) {
                float vv = vs2[sl][el];
                float4 kk = *(const float4*)&ks[sl][rs * 4];
                mdelta[0] += kk.x * vv; mdelta[1] += kk.y * vv;
                mdelta[2] += kk.z * vv; mdelta[3] += kk.w * vv;
                zd += ks[sl][eg];
            }
        }
        __syncthreads();
#pragma unroll
        for (int j = 0; j < 4; ++j) vs2[rs * 4 + j][el] = mdelta[j];
        __syncthreads();
#pragma unroll
        for (int d = 0; d < 64; ++d) Mreg[d] += vs2[d][el];
        zreg += zd;
    }
}

// ---------------- Scan phase 2: A-readout from prefixes; XT += g*A ----
__global__ __launch_bounds__(256) void scan_s2(
    const float* __restrict__ q, const float* __restrict__ Mpre,
    const float* __restrict__ zpre, const float* __restrict__ beta,
    float* __restrict__ XT)
{
    const int bh = blockIdx.z; const int b = bh >> 4, h = bh & 15;
    const int c = blockIdx.y;
    const int tile = blockIdx.x;          // 0..7
    const int tid = threadIdx.x;
    const int lane = tid & 63;            // e
    const int w = tid >> 6;               // wave 0..3
    const float g = 1.f / (1.f + __expf(-beta[0]));

    __shared__ float qs[64][68];

    float Mreg[64];
    const float* mp = Mpre + ((size_t)(bh * Cz + c) * 64) * 64;
#pragma unroll
    for (int d = 0; d < 64; ++d) Mreg[d] = mp[(size_t)d * 64 + lane];
    const float zv = zpre[(size_t)(bh * Cz + c) * 64 + lane];

    const size_t boff = (size_t)b * Lz * Dz + h * DHz;
    const int s0 = c * Sz + tile * 64;
#pragma unroll
    for (int it = 0; it < 4; ++it) {
        int idx = it * 256 + tid;
        int r = idx >> 4, f = (idx & 15) * 4;
        float4 t = *(const float4*)(q + boff + (size_t)(s0 + r) * Dz + f);
        qs[r][f + 0] = sigmaf(t.x); qs[r][f + 1] = sigmaf(t.y);
        qs[r][f + 2] = sigmaf(t.z); qs[r][f + 3] = sigmaf(t.w);
    }
    __syncthreads();

    const int e_out = c * 128 + h * 8 + tile;
    float* xp = XT + ((size_t)b * Dz + e_out) * Lz;
    for (int i = 0; i < 16; ++i) {
        const int sl = w * 16 + i;
        float num = 0.f, ssq = 0.f;
#pragma unroll
        for (int d = 0; d < 64; d += 4) {
            float4 qq = *(const float4*)&qs[sl][d];
            num += qq.x * Mreg[d] + qq.y * Mreg[d + 1]
                 + qq.z * Mreg[d + 2] + qq.w * Mreg[d + 3];
            ssq += qq.x + qq.y + qq.z + qq.w;
        }
        float A = num / (ssq * zv + 1e-6f);
        size_t xoff = (size_t)sl * 64 + lane;
        xp[xoff] += g * A;
    }
}

extern "C" void kernel_launch(void* const* d_in, const int* in_sizes, int n_in,
                              void* d_out, int out_size, void* d_ws, size_t ws_size,
                              hipStream_t stream)
{
    (void)in_sizes; (void)n_in; (void)out_size; (void)ws_size;
    const float* query  = (const float*)d_in[0];
    const float* key_in = (const float*)d_in[1];
    const float* value  = (const float*)d_in[2];
    const float* Wq = (const float*)d_in[3];
    const float* bq = (const float*)d_in[4];
    const float* Wk = (const float*)d_in[5];
    const float* bk = (const float*)d_in[6];
    const float* Wv = (const float*)d_in[7];
    const float* bv = (const float*)d_in[8];
    const float* Wo = (const float*)d_in[9];
    const float* bo = (const float*)d_in[10];
    const float* beta = (const float*)d_in[11];
    float* out = (float*)d_out;

    const size_t NE = (size_t)Bz * Lz * Dz;            // 16,777,216 per buffer
    const size_t NM = (size_t)64 * Cz * 64 * 64;       // M prefixes
    float* qb = (float*)d_ws;
    float* kb = qb + NE;
    float* vb = kb + NE;
    float* Mpre = vb + NE;
    float* zpre = Mpre + NM;
    float* XT = vb;                       // vb dead after scan_s1 -> reused as XT

    // d_out (64MB) scratch until final GEMM: Wt q/k/v (12MB) + vth (32MB)
    unsigned short* u0  = (unsigned short*)d_out;
    unsigned short* Wtq = u0;
    unsigned short* Wtk = u0 + 2 * 1048576;
    unsigned short* Wtv = u0 + 4 * 1048576;
    unsigned short* vth = u0 + 6 * 1048576;
    unsigned short* Wto = (unsigned short*)kb;   // kb dead after attn
    unsigned short* XTt = (unsigned short*)qb;   // qb dead after scan_s2 (64MB = 2 planes)

    wt_kernel<<<dim3(16, 16), 256, 0, stream>>>(Wq, Wtq);
    wt_kernel<<<dim3(16, 16), 256, 0, stream>>>(Wk, Wtk);
    wt_kernel<<<dim3(16, 16), 256, 0, stream>>>(Wv, Wtv);
    mm_split<true, true><<<dim3(8, 128), 256, 0, stream>>>(query,  nullptr, Wtq, bq, qb);
    mm_split<true, true><<<dim3(8, 128), 256, 0, stream>>>(key_in, nullptr, Wtk, bk, kb);
    mm_split<true, true><<<dim3(8, 128), 256, 0, stream>>>(value,  nullptr, Wtv, bv, vb);
    vt_kernel<<<dim3(Lz / 64, Hz, Bz), 256, 0, stream>>>(vb, vth);
    scan_s1<<<dim3(256), 256, 0, stream>>>(kb, vb, Mpre, zpre);
    attn_kernel<<<dim3(4, Cz, Bz * Hz), 256, 0, stream>>>(qb, kb, vth, beta, XT);
    scan_s2<<<dim3(8, Cz, Bz * Hz), 256, 0, stream>>>(qb, Mpre, zpre, beta, XT);
    wt_kernel<<<dim3(16, 16), 256, 0, stream>>>(Wo, Wto);
    xtt_kernel<<<dim3(Lz / 64, Dz / 64, Bz), 256, 0, stream>>>(XT, XTt);
    mm_split<false, false><<<dim3(8, 128), 256, 0, stream>>>(nullptr, XTt, Wto, bo, out);
}

// Round 4
// 1881.641 us; speedup vs baseline: 2.0694x; 1.0178x over previous
//
#include <hip/hip_runtime.h>
#include <math.h>

#define Bz 4
#define Lz 4096
#define Dz 1024
#define Hz 16
#define Cz 8
#define Sz 512
#define DHz 64

typedef __bf16 bf16x8 __attribute__((ext_vector_type(8)));
typedef float f32x16 __attribute__((ext_vector_type(16)));

__device__ __forceinline__ float sigmaf(float x) {
    return x >= 0.f ? x : expm1f(x);
}

// pack two f32 -> one dword of 2 bf16 (RNE), lo = a, hi = b
__device__ __forceinline__ unsigned pkbf(float a, float b) {
    unsigned r;
    asm("v_cvt_pk_bf16_f32 %0, %1, %2" : "=v"(r) : "v"(a), "v"(b));
    return r;
}

// ---------------- W transpose+split: dst[n][k] (hi plane, then lo plane) <- W[k][n]
__global__ __launch_bounds__(256) void wt_kernel(
    const float* __restrict__ W, unsigned short* __restrict__ dst)
{
    __shared__ float Ls[64][65];
    const int tid = threadIdx.x;
    const int n0 = blockIdx.x * 64, k0 = blockIdx.y * 64;
#pragma unroll
    for (int i = 0; i < 4; ++i) {
        int idx = i * 256 + tid;
        int r = idx >> 4, c4 = (idx & 15) * 4;
        float4 t = *(const float4*)&W[(size_t)(k0 + r) * 1024 + n0 + c4];
        Ls[r][c4] = t.x; Ls[r][c4 + 1] = t.y; Ls[r][c4 + 2] = t.z; Ls[r][c4 + 3] = t.w;
    }
    __syncthreads();
    const int n = tid >> 2, j0 = (tid & 3) * 16;
    unsigned uh[8], ul[8];
#pragma unroll
    for (int j = 0; j < 8; ++j) {
        float a = Ls[j0 + 2 * j][n], b = Ls[j0 + 2 * j + 1][n];
        unsigned h = pkbf(a, b);
        float ra = a - __uint_as_float(h << 16);
        float rb = b - __uint_as_float(h & 0xffff0000u);
        uh[j] = h; ul[j] = pkbf(ra, rb);
    }
    unsigned short* op = dst + (size_t)(n0 + n) * 1024 + k0 + j0;
    uint4 o;
    o.x = uh[0]; o.y = uh[1]; o.z = uh[2]; o.w = uh[3]; *(uint4*)op = o;
    o.x = uh[4]; o.y = uh[5]; o.z = uh[6]; o.w = uh[7]; *(uint4*)(op + 8) = o;
    op += 1048576;
    o.x = ul[0]; o.y = ul[1]; o.z = ul[2]; o.w = ul[3]; *(uint4*)op = o;
    o.x = ul[4]; o.y = ul[5]; o.z = ul[6]; o.w = ul[7]; *(uint4*)(op + 8) = o;
}

// ---------------- XT transpose+split: dst[(b*L+l)][e] (hi, lo planes) <- XT[b][e][l]
__global__ __launch_bounds__(256) void xtt_kernel(
    const float* __restrict__ XT, unsigned short* __restrict__ dst)
{
    __shared__ float Ls[64][65];
    const int tid = threadIdx.x;
    const int b = blockIdx.z, e0 = blockIdx.y * 64, l0 = blockIdx.x * 64;
#pragma unroll
    for (int i = 0; i < 4; ++i) {
        int idx = i * 256 + tid;
        int r = idx >> 4, c4 = (idx & 15) * 4;
        float4 t = *(const float4*)&XT[((size_t)b * 1024 + e0 + r) * 4096 + l0 + c4];
        Ls[r][c4] = t.x; Ls[r][c4 + 1] = t.y; Ls[r][c4 + 2] = t.z; Ls[r][c4 + 3] = t.w;
    }
    __syncthreads();
    const int l = tid >> 2, j0 = (tid & 3) * 16;
    unsigned uh[8], ul[8];
#pragma unroll
    for (int j = 0; j < 8; ++j) {
        float a = Ls[j0 + 2 * j][l], b2 = Ls[j0 + 2 * j + 1][l];
        unsigned h = pkbf(a, b2);
        float ra = a - __uint_as_float(h << 16);
        float rb = b2 - __uint_as_float(h & 0xffff0000u);
        uh[j] = h; ul[j] = pkbf(ra, rb);
    }
    unsigned short* op = dst + ((size_t)(b * 4096 + l0 + l)) * 1024 + e0 + j0;
    uint4 o;
    o.x = uh[0]; o.y = uh[1]; o.z = uh[2]; o.w = uh[3]; *(uint4*)op = o;
    o.x = uh[4]; o.y = uh[5]; o.z = uh[6]; o.w = uh[7]; *(uint4*)(op + 8) = o;
    op += 16777216;
    o.x = ul[0]; o.y = ul[1]; o.z = ul[2]; o.w = ul[3]; *(uint4*)op = o;
    o.x = ul[4]; o.y = ul[5]; o.z = ul[6]; o.w = ul[7]; *(uint4*)(op + 8) = o;
}

// ---------------- Split-bf16 MFMA GEMM: C[m][n] = sum_k A[m][k]*Bt[n][k] + bias[n]
// M=16384, K=N=1024. Bt pre-split bf16 planes [2][1024][1024] (n-major, k contig).
// ASPLIT: A is fp32, split hi/lo on the fly; else A is pre-split planes [2][16384][1024].
// FULL4: include Al*Bl (full fp32-class, rel err ~2^-24); else 3 terms (~2^-16).
template<bool ASPLIT, bool FULL4>
__global__ __launch_bounds__(256) void mm_split(
    const float* __restrict__ Af32, const unsigned short* __restrict__ Abf,
    const unsigned short* __restrict__ Bt,
    const float* __restrict__ bias, float* __restrict__ C)
{
    __shared__ __align__(16) unsigned short Ah[128 * 64];
    __shared__ __align__(16) unsigned short Al[128 * 64];
    __shared__ __align__(16) unsigned short Bh[128 * 64];
    __shared__ __align__(16) unsigned short Bl[128 * 64];
    const int tid = threadIdx.x;
    const int m0 = blockIdx.y * 128, n0 = blockIdx.x * 128;
    const int lane = tid & 63, w = tid >> 6;
    const int lq = lane & 31, hi = lane >> 5;
    const int wm = (w >> 1) * 64, wn = (w & 1) * 64;

    f32x16 acc[2][2];
#pragma unroll
    for (int i = 0; i < 2; ++i)
#pragma unroll
        for (int j = 0; j < 2; ++j)
#pragma unroll
            for (int r = 0; r < 16; ++r) acc[i][j][r] = 0.f;

    for (int kb = 0; kb < 1024; kb += 64) {
        __syncthreads();
        if constexpr (ASPLIT) {
#pragma unroll
            for (int i = 0; i < 8; ++i) {
                int idx = i * 256 + tid;
                int r = idx >> 4, fq = idx & 15;
                float4 a = *(const float4*)(Af32 + (size_t)(m0 + r) * 1024 + kb + fq * 4);
                unsigned h0 = pkbf(a.x, a.y), h1 = pkbf(a.z, a.w);
                float rx = a.x - __uint_as_float(h0 << 16);
                float ry = a.y - __uint_as_float(h0 & 0xffff0000u);
                float rz = a.z - __uint_as_float(h1 << 16);
                float rw = a.w - __uint_as_float(h1 & 0xffff0000u);
                unsigned l0 = pkbf(rx, ry), l1 = pkbf(rz, rw);
                int boff = r * 128 + ((fq * 8) ^ ((r & 7) << 4));
                uint2 th; th.x = h0; th.y = h1;
                uint2 tl; tl.x = l0; tl.y = l1;
                *(uint2*)((char*)Ah + boff) = th;
                *(uint2*)((char*)Al + boff) = tl;
            }
        } else {
#pragma unroll
            for (int p = 0; p < 2; ++p) {
                const unsigned short* ap = Abf + (size_t)p * 16777216 + (size_t)m0 * 1024 + kb;
                unsigned short* dst = p ? Al : Ah;
#pragma unroll
                for (int i = 0; i < 4; ++i) {
                    int idx = i * 256 + tid;
                    int r = idx >> 3, uq = idx & 7;
                    uint4 d = *(const uint4*)(ap + (size_t)r * 1024 + uq * 8);
                    *(uint4*)((char*)dst + r * 128 + ((uq * 16) ^ ((r & 7) << 4))) = d;
                }
            }
        }
#pragma unroll
        for (int p = 0; p < 2; ++p) {
            const unsigned short* bp = Bt + (size_t)p * 1048576 + (size_t)n0 * 1024 + kb;
            unsigned short* dst = p ? Bl : Bh;
#pragma unroll
            for (int i = 0; i < 4; ++i) {
                int idx = i * 256 + tid;
                int r = idx >> 3, uq = idx & 7;
                uint4 d = *(const uint4*)(bp + (size_t)r * 1024 + uq * 8);
                *(uint4*)((char*)dst + r * 128 + ((uq * 16) ^ ((r & 7) << 4))) = d;
            }
        }
        __syncthreads();
#pragma unroll
        for (int kt = 0; kt < 4; ++kt) {
            bf16x8 fah[2], fal[2], fbh[2], fbl[2];
            const int cb = kt * 32 + hi * 16;
#pragma unroll
            for (int mb = 0; mb < 2; ++mb) {
                int r = wm + mb * 32 + lq;
                int off = r * 128 + (cb ^ ((r & 7) << 4));
                fah[mb] = *(const bf16x8*)((const char*)Ah + off);
                fal[mb] = *(const bf16x8*)((const char*)Al + off);
            }
#pragma unroll
            for (int nb = 0; nb < 2; ++nb) {
                int r = wn + nb * 32 + lq;
                int off = r * 128 + (cb ^ ((r & 7) << 4));
                fbh[nb] = *(const bf16x8*)((const char*)Bh + off);
                fbl[nb] = *(const bf16x8*)((const char*)Bl + off);
            }
#pragma unroll
            for (int mb = 0; mb < 2; ++mb)
#pragma unroll
                for (int nb = 0; nb < 2; ++nb) {
                    acc[mb][nb] = __builtin_amdgcn_mfma_f32_32x32x16_bf16(fah[mb], fbh[nb], acc[mb][nb], 0, 0, 0);
                    acc[mb][nb] = __builtin_amdgcn_mfma_f32_32x32x16_bf16(fah[mb], fbl[nb], acc[mb][nb], 0, 0, 0);
                    acc[mb][nb] = __builtin_amdgcn_mfma_f32_32x32x16_bf16(fal[mb], fbh[nb], acc[mb][nb], 0, 0, 0);
                    if constexpr (FULL4)
                        acc[mb][nb] = __builtin_amdgcn_mfma_f32_32x32x16_bf16(fal[mb], fbl[nb], acc[mb][nb], 0, 0, 0);
                }
        }
    }
#pragma unroll
    for (int mb = 0; mb < 2; ++mb)
#pragma unroll
        for (int nb = 0; nb < 2; ++nb) {
            int n = n0 + wn + nb * 32 + lq;
            float bn = bias[n];
#pragma unroll
            for (int r = 0; r < 16; ++r) {
                int m = m0 + wm + mb * 32 + (r & 3) + 8 * (r >> 2) + 4 * hi;
                C[(size_t)m * 1024 + n] = acc[mb][nb][r] + bn;
            }
        }
}

// ---------------- V transpose to bf16: vth[b][h][d][L] <- v[b][l][h*64+d] ----
__global__ __launch_bounds__(256) void vt_kernel(
    const float* __restrict__ v, unsigned short* __restrict__ vth)
{
    const int b = blockIdx.z, h = blockIdx.y, l0 = blockIdx.x * 64;
    const int tid = threadIdx.x;
    __shared__ float Ls[64][65];
#pragma unroll
    for (int it = 0; it < 4; ++it) {
        int idx = it * 256 + tid;
        int r = idx >> 4, c4 = (idx & 15) * 4;
        float4 t = *(const float4*)&v[((size_t)b * Lz + l0 + r) * Dz + h * DHz + c4];
        Ls[r][c4] = t.x; Ls[r][c4 + 1] = t.y; Ls[r][c4 + 2] = t.z; Ls[r][c4 + 3] = t.w;
    }
    __syncthreads();
    const int d = tid >> 2, j0 = (tid & 3) * 16;
    unsigned u[8];
#pragma unroll
    for (int j = 0; j < 8; ++j)
        u[j] = pkbf(Ls[j0 + 2 * j][d], Ls[j0 + 2 * j + 1][d]);
    unsigned short* op = vth + ((size_t)(b * Hz + h) * 64 + d) * Lz + l0 + j0;
    uint4 o0; o0.x = u[0]; o0.y = u[1]; o0.z = u[2]; o0.w = u[3];
    uint4 o1; o1.x = u[4]; o1.y = u[5]; o1.z = u[6]; o1.w = u[7];
    *(uint4*)op = o0;
    *(uint4*)(op + 8) = o1;
}

// ---------------- MFMA local attention; writes (1-g)*dot into XT[b][e][l] ----
__global__ __launch_bounds__(256) void attn_kernel(
    const float* __restrict__ q, const float* __restrict__ k,
    const unsigned short* __restrict__ vth,
    const float* __restrict__ beta, float* __restrict__ XT)
{
    const int bh = blockIdx.z; const int b = bh >> 4, h = bh & 15;
    const int c = blockIdx.y;
    const int qt = blockIdx.x;            // q-tile 0..3 (128 rows each)
    const int tid = threadIdx.x;
    const int lane = tid & 63;
    const int w = tid >> 6;
    const int lq = lane & 31;
    const int hi = lane >> 5;
    const float g = 1.f / (1.f + __expf(-beta[0]));

    __shared__ __align__(16) unsigned short Qs[128 * 64];  // bf16, swizzled rows of 128B
    __shared__ __align__(16) unsigned short Ks[64 * 64];   // bf16 [t][d]
    __shared__ __align__(16) unsigned short Vs[64 * 64];   // bf16 [d][t]
    __shared__ float lsum_lds[128];

    const size_t rowb = (size_t)b * Lz * Dz + (size_t)h * DHz;

    // ---- stage Q tile (128 rows) fp32 -> bf16, XOR-swizzled ----
    {
        const int r = tid >> 2, c4 = tid & 3;
#pragma unroll
        for (int p = 0; p < 2; ++p) {
            int rr = p * 64 + r;
            const float* qp = q + rowb + (size_t)(c * Sz + qt * 128 + rr) * Dz + c4 * 16;
            float4 f0 = ((const float4*)qp)[0];
            float4 f1 = ((const float4*)qp)[1];
            float4 f2 = ((const float4*)qp)[2];
            float4 f3 = ((const float4*)qp)[3];
            uint4 u0, u1;
            u0.x = pkbf(f0.x, f0.y); u0.y = pkbf(f0.z, f0.w);
            u0.z = pkbf(f1.x, f1.y); u0.w = pkbf(f1.z, f1.w);
            u1.x = pkbf(f2.x, f2.y); u1.y = pkbf(f2.z, f2.w);
            u1.z = pkbf(f3.x, f3.y); u1.w = pkbf(f3.z, f3.w);
            int base = rr * 128;
            *(uint4*)((char*)Qs + base + ((c4 * 32)      ^ ((rr & 7) << 4))) = u0;
            *(uint4*)((char*)Qs + base + ((c4 * 32 + 16) ^ ((rr & 7) << 4))) = u1;
        }
    }
    __syncthreads();
    // Q B-fragments: lane holds Q[q = w*32+lq][d = 8*hi + i + 16*ck]
    bf16x8 qf[4];
#pragma unroll
    for (int ck = 0; ck < 4; ++ck) {
        int rr = w * 32 + lq;
        qf[ck] = *(const bf16x8*)((const char*)Qs + rr * 128 + ((ck * 32 + hi * 16) ^ ((rr & 7) << 4)));
    }

    f32x16 acc0, acc1;
#pragma unroll
    for (int r = 0; r < 16; ++r) { acc0[r] = 0.f; acc1[r] = 0.f; }
    float lsum = 0.f;

    for (int kt = 0; kt < 8; ++kt) {
        __syncthreads();
        // ---- stage K (fp32->bf16, [t][d]) and V (bf16 from vth, [d][t]), swizzled ----
        {
            const int r = tid >> 2, c4 = tid & 3;
            const float* kp = k + rowb + (size_t)(c * Sz + kt * 64 + r) * Dz + c4 * 16;
            float4 f0 = ((const float4*)kp)[0];
            float4 f1 = ((const float4*)kp)[1];
            float4 f2 = ((const float4*)kp)[2];
            float4 f3 = ((const float4*)kp)[3];
            uint4 u0, u1;
            u0.x = pkbf(f0.x, f0.y); u0.y = pkbf(f0.z, f0.w);
            u0.z = pkbf(f1.x, f1.y); u0.w = pkbf(f1.z, f1.w);
            u1.x = pkbf(f2.x, f2.y); u1.y = pkbf(f2.z, f2.w);
            u1.z = pkbf(f3.x, f3.y); u1.w = pkbf(f3.z, f3.w);
            int base = r * 128;
            *(uint4*)((char*)Ks + base + ((c4 * 32)      ^ ((r & 7) << 4))) = u0;
            *(uint4*)((char*)Ks + base + ((c4 * 32 + 16) ^ ((r & 7) << 4))) = u1;
            // V: row index r is d, columns are t (already bf16 in vth)
            const unsigned short* vp = vth + ((size_t)(b * Hz + h) * 64 + r) * Lz + c * Sz + kt * 64 + c4 * 16;
            uint4 v0 = ((const uint4*)vp)[0];
            uint4 v1 = ((const uint4*)vp)[1];
            *(uint4*)((char*)Vs + base + ((c4 * 32)      ^ ((r & 7) << 4))) = v0;
            *(uint4*)((char*)Vs + base + ((c4 * 32 + 16) ^ ((r & 7) << 4))) = v1;
        }
        __syncthreads();

        bf16x8 pA[4];
#pragma unroll
        for (int tb = 0; tb < 2; ++tb) {
            f32x16 pt;
#pragma unroll
            for (int r = 0; r < 16; ++r) pt[r] = 0.f;
#pragma unroll
            for (int ck = 0; ck < 4; ++ck) {
                int rr = tb * 32 + lq;
                bf16x8 ka = *(const bf16x8*)((const char*)Ks + rr * 128 + ((ck * 32 + hi * 16) ^ ((rr & 7) << 4)));
                // Pt[t][q] += K[t][d] * Q[q][d]
                pt = __builtin_amdgcn_mfma_f32_32x32x16_bf16(ka, qf[ck], pt, 0, 0, 0);
            }
            // p = exp(logit*scale); lane covers t = tb*32 + (r&3)+8*(r>>2)+4*hi for q = w*32+lq
            float p[16];
#pragma unroll
            for (int r = 0; r < 16; ++r) { p[r] = __expf(pt[r] * 0.125f); lsum += p[r]; }
            // repack D-layout (col=q) -> A-layout (m=q, k=t) via cvt_pk + permlane32_swap
#pragma unroll
            for (int cc = 0; cc < 2; ++cc) {
                unsigned u0 = pkbf(p[8 * cc + 0], p[8 * cc + 1]);
                unsigned u1 = pkbf(p[8 * cc + 2], p[8 * cc + 3]);
                unsigned u2 = pkbf(p[8 * cc + 4], p[8 * cc + 5]);
                unsigned u3 = pkbf(p[8 * cc + 6], p[8 * cc + 7]);
                asm volatile("v_permlane32_swap_b32 %0, %1" : "+v"(u0), "+v"(u2));
                asm volatile("v_permlane32_swap_b32 %0, %1" : "+v"(u1), "+v"(u3));
                union { unsigned u[4]; bf16x8 v; } pa;
                pa.u[0] = u0; pa.u[1] = u1; pa.u[2] = u2; pa.u[3] = u3;
                pA[tb * 2 + cc] = pa.v;
            }
        }
        // PV: out[q][d] += P[q][t] * V[t][d]
#pragma unroll
        for (int ck = 0; ck < 4; ++ck) {
            int r0 = lq;
            bf16x8 vf0 = *(const bf16x8*)((const char*)Vs + r0 * 128 + ((ck * 32 + hi * 16) ^ ((r0 & 7) << 4)));
            acc0 = __builtin_amdgcn_mfma_f32_32x32x16_bf16(pA[ck], vf0, acc0, 0, 0, 0);
            int r1 = 32 + lq;
            bf16x8 vf1 = *(const bf16x8*)((const char*)Vs + r1 * 128 + ((ck * 32 + hi * 16) ^ ((r1 & 7) << 4)));
            acc1 = __builtin_amdgcn_mfma_f32_32x32x16_bf16(pA[ck], vf1, acc1, 0, 0, 0);
        }
    }

    // finish row sums: lane and lane^32 each hold half the t's of row q=w*32+lq
    lsum += __shfl_xor(lsum, 32);
    if (hi == 0) lsum_lds[w * 32 + lq] = lsum;
    __syncthreads();

    const float invg = 1.f - g;
#pragma unroll
    for (int r = 0; r < 16; ++r) {
        int ql = (r & 3) + 8 * (r >> 2) + 4 * hi;
        float sc = invg / lsum_lds[w * 32 + ql];
        int s = qt * 128 + w * 32 + ql;
        int e = c * 128 + h * 8 + (s >> 6);
        float* xp = XT + ((size_t)b * Dz + e) * Lz + (s & 63) * 64;
        xp[lq]      = acc0[r] * sc;
        xp[32 + lq] = acc1[r] * sc;
    }
}

// ---------------- Scan phase 1: evolve M,z; store per-segment prefixes ----
// grid: 512 blocks = bh(64) x esplit(8); block 256 threads (el=tid&7, rs=tid>>3).
// NOTE: bit-identical arithmetic to the es=4 version — each output element's
// FLOP sequence (d-order, sl-order, chunk-order, segment-order) is unchanged;
// only the thread->element partition changed (occupancy 1 -> 2 blocks/CU).
__global__ __launch_bounds__(256) void scan_s1(
    const float* __restrict__ k, const float* __restrict__ v,
    float* __restrict__ Mpre, float* __restrict__ zpre)
{
    const int bx = blockIdx.x;
    const int bh = bx >> 3, es = bx & 7;
    const int b = bh >> 4, h = bh & 15;
    const int tid = threadIdx.x;
    const int el = tid & 7;           // e-local 0..7
    const int rs = tid >> 3;          // 0..31
    const int eg = es * 8 + el;       // e within head, 0..63

    __shared__ float ks[64][68];      // sigma(k) rows, padded (+4) -> conflict-free
    __shared__ float vs2[64][8];      // v slice, later holds val, later mdelta exchange

    float Mreg[64];                   // column eg of M
#pragma unroll
    for (int d = 0; d < 64; ++d) Mreg[d] = 0.f;
    float zreg = 0.f;

    const size_t boff = (size_t)b * Lz * Dz + h * DHz;

    for (int c = 0; c < Cz; ++c) {
        {
            float* mp = Mpre + ((size_t)(bh * Cz + c) * 64) * 64;
#pragma unroll
            for (int j = 0; j < 2; ++j) {
                int d = rs * 2 + j;
                mp[(size_t)d * 64 + eg] = Mreg[d];
            }
            if (rs == 0) zpre[(size_t)(bh * Cz + c) * 64 + eg] = zreg;
        }
        float mdelta[2] = {0.f, 0.f};
        float zd = 0.f;

        for (int ch = 0; ch < 8; ++ch) {
            const int s0 = c * Sz + ch * 64;
            __syncthreads();
            // stage sigma(k): 64 rows x 64 d
#pragma unroll
            for (int it = 0; it < 4; ++it) {
                int idx = it * 256 + tid;
                int r = idx >> 4, f = (idx & 15) * 4;
                float4 t = *(const float4*)(k + boff + (size_t)(s0 + r) * Dz + f);
                ks[r][f + 0] = sigmaf(t.x); ks[r][f + 1] = sigmaf(t.y);
                ks[r][f + 2] = sigmaf(t.z); ks[r][f + 3] = sigmaf(t.w);
            }
            // stage v slice: 64 rows x 8 cols (this block's e-range)
            {
                int r = tid >> 2, f = (tid & 3) * 2;
                float2 t = *(const float2*)(v + boff + (size_t)(s0 + r) * Dz + es * 8 + f);
                *(float2*)&vs2[r][f] = t;
            }
            __syncthreads();
            // val = v - (sigma(k)@M)/(ssk*z+eps), each thread owns (sl=rs*2+j, el)
#pragma unroll
            for (int j = 0; j < 2; ++j) {
                const int sl = rs * 2 + j;
                float numk = 0.f, ssk = 0.f;
#pragma unroll
                for (int d = 0; d < 64; d += 4) {
                    float4 kk = *(const float4*)&ks[sl][d];
                    numk += kk.x * Mreg[d] + kk.y * Mreg[d + 1]
                          + kk.z * Mreg[d + 2] + kk.w * Mreg[d + 3];
                    ssk += kk.x + kk.y + kk.z + kk.w;
                }
                vs2[sl][el] = vs2[sl][el] - numk / (ssk * zreg + 1e-6f);
            }
            __syncthreads();
            // mdelta[d=rs*2+j][eg] += sum_sl sigma(k)[sl][d]*val[sl][eg]; also z delta
            for (int sl = 0; sl < 64; ++sl) {
                float vv = vs2[sl][el];
                float2 kk = *(const float2*)&ks[sl][rs * 2];
                mdelta[0] += kk.x * vv; mdelta[1] += kk.y * vv;
                zd += ks[sl][eg];
            }
        }
        // apply deltas: exchange mdelta columns via vs2
        __syncthreads();
#pragma unroll
        for (int j = 0; j < 2; ++j) vs2[rs * 2 + j][el] = mdelta[j];
        __syncthreads();
#pragma unroll
        for (int d = 0; d < 64; ++d) Mreg[d] += vs2[d][el];
        zreg += zd;
    }
}

// ---------------- Scan phase 2: A-readout from prefixes; XT += g*A ----
__global__ __launch_bounds__(256) void scan_s2(
    const float* __restrict__ q, const float* __restrict__ Mpre,
    const float* __restrict__ zpre, const float* __restrict__ beta,
    float* __restrict__ XT)
{
    const int bh = blockIdx.z; const int b = bh >> 4, h = bh & 15;
    const int c = blockIdx.y;
    const int tile = blockIdx.x;          // 0..7
    const int tid = threadIdx.x;
    const int lane = tid & 63;            // e
    const int w = tid >> 6;               // wave 0..3
    const float g = 1.f / (1.f + __expf(-beta[0]));

    __shared__ float qs[64][68];

    float Mreg[64];
    const float* mp = Mpre + ((size_t)(bh * Cz + c) * 64) * 64;
#pragma unroll
    for (int d = 0; d < 64; ++d) Mreg[d] = mp[(size_t)d * 64 + lane];
    const float zv = zpre[(size_t)(bh * Cz + c) * 64 + lane];

    const size_t boff = (size_t)b * Lz * Dz + h * DHz;
    const int s0 = c * Sz + tile * 64;
#pragma unroll
    for (int it = 0; it < 4; ++it) {
        int idx = it * 256 + tid;
        int r = idx >> 4, f = (idx & 15) * 4;
        float4 t = *(const float4*)(q + boff + (size_t)(s0 + r) * Dz + f);
        qs[r][f + 0] = sigmaf(t.x); qs[r][f + 1] = sigmaf(t.y);
        qs[r][f + 2] = sigmaf(t.z); qs[r][f + 3] = sigmaf(t.w);
    }
    __syncthreads();

    const int e_out = c * 128 + h * 8 + tile;
    float* xp = XT + ((size_t)b * Dz + e_out) * Lz;
    for (int i = 0; i < 16; ++i) {
        const int sl = w * 16 + i;
        float num = 0.f, ssq = 0.f;
#pragma unroll
        for (int d = 0; d < 64; d += 4) {
            float4 qq = *(const float4*)&qs[sl][d];
            num += qq.x * Mreg[d] + qq.y * Mreg[d + 1]
                 + qq.z * Mreg[d + 2] + qq.w * Mreg[d + 3];
            ssq += qq.x + qq.y + qq.z + qq.w;
        }
        float A = num / (ssq * zv + 1e-6f);
        size_t xoff = (size_t)sl * 64 + lane;
        xp[xoff] += g * A;
    }
}

extern "C" void kernel_launch(void* const* d_in, const int* in_sizes, int n_in,
                              void* d_out, int out_size, void* d_ws, size_t ws_size,
                              hipStream_t stream)
{
    (void)in_sizes; (void)n_in; (void)out_size; (void)ws_size;
    const float* query  = (const float*)d_in[0];
    const float* key_in = (const float*)d_in[1];
    const float* value  = (const float*)d_in[2];
    const float* Wq = (const float*)d_in[3];
    const float* bq = (const float*)d_in[4];
    const float* Wk = (const float*)d_in[5];
    const float* bk = (const float*)d_in[6];
    const float* Wv = (const float*)d_in[7];
    const float* bv = (const float*)d_in[8];
    const float* Wo = (const float*)d_in[9];
    const float* bo = (const float*)d_in[10];
    const float* beta = (const float*)d_in[11];
    float* out = (float*)d_out;

    const size_t NE = (size_t)Bz * Lz * Dz;            // 16,777,216 per buffer
    const size_t NM = (size_t)64 * Cz * 64 * 64;       // M prefixes
    float* qb = (float*)d_ws;
    float* kb = qb + NE;
    float* vb = kb + NE;
    float* Mpre = vb + NE;
    float* zpre = Mpre + NM;
    float* XT = vb;                       // vb dead after scan_s1 -> reused as XT

    // d_out (64MB) scratch until final GEMM: Wt q/k/v (12MB) + vth (32MB)
    unsigned short* u0  = (unsigned short*)d_out;
    unsigned short* Wtq = u0;
    unsigned short* Wtk = u0 + 2 * 1048576;
    unsigned short* Wtv = u0 + 4 * 1048576;
    unsigned short* vth = u0 + 6 * 1048576;
    unsigned short* Wto = (unsigned short*)kb;   // kb dead after attn
    unsigned short* XTt = (unsigned short*)qb;   // qb dead after scan_s2 (64MB = 2 planes)

    wt_kernel<<<dim3(16, 16), 256, 0, stream>>>(Wq, Wtq);
    wt_kernel<<<dim3(16, 16), 256, 0, stream>>>(Wk, Wtk);
    wt_kernel<<<dim3(16, 16), 256, 0, stream>>>(Wv, Wtv);
    mm_split<true, true><<<dim3(8, 128), 256, 0, stream>>>(query,  nullptr, Wtq, bq, qb);
    mm_split<true, true><<<dim3(8, 128), 256, 0, stream>>>(key_in, nullptr, Wtk, bk, kb);
    mm_split<true, true><<<dim3(8, 128), 256, 0, stream>>>(value,  nullptr, Wtv, bv, vb);
    vt_kernel<<<dim3(Lz / 64, Hz, Bz), 256, 0, stream>>>(vb, vth);
    scan_s1<<<dim3(512), 256, 0, stream>>>(kb, vb, Mpre, zpre);
    attn_kernel<<<dim3(4, Cz, Bz * Hz), 256, 0, stream>>>(qb, kb, vth, beta, XT);
    scan_s2<<<dim3(8, Cz, Bz * Hz), 256, 0, stream>>>(qb, Mpre, zpre, beta, XT);
    wt_kernel<<<dim3(16, 16), 256, 0, stream>>>(Wo, Wto);
    xtt_kernel<<<dim3(Lz / 64, Dz / 64, Bz), 256, 0, stream>>>(XT, XTt);
    mm_split<false, false><<<dim3(8, 128), 256, 0, stream>>>(nullptr, XTt, Wto, bo, out);
}

// Round 7
// 1670.645 us; speedup vs baseline: 2.3307x; 1.1263x over previous
//
#include <hip/hip_runtime.h>
#include <math.h>

#define Bz 4
#define Lz 4096
#define Dz 1024
#define Hz 16
#define Cz 8
#define Sz 512
#define DHz 64

typedef __bf16 bf16x8 __attribute__((ext_vector_type(8)));
typedef float f32x16 __attribute__((ext_vector_type(16)));

__device__ __forceinline__ float sigmaf(float x) {
    return x >= 0.f ? x : expm1f(x);
}

// pack two f32 -> one dword of 2 bf16 (RNE), lo = a, hi = b
__device__ __forceinline__ unsigned pkbf(float a, float b) {
    unsigned r;
    asm("v_cvt_pk_bf16_f32 %0, %1, %2" : "=v"(r) : "v"(a), "v"(b));
    return r;
}

// ---------------- W transpose+split: dst[n][k] (hi plane, then lo plane) <- W[k][n]
__global__ __launch_bounds__(256) void wt_kernel(
    const float* __restrict__ W, unsigned short* __restrict__ dst)
{
    __shared__ float Ls[64][65];
    const int tid = threadIdx.x;
    const int n0 = blockIdx.x * 64, k0 = blockIdx.y * 64;
#pragma unroll
    for (int i = 0; i < 4; ++i) {
        int idx = i * 256 + tid;
        int r = idx >> 4, c4 = (idx & 15) * 4;
        float4 t = *(const float4*)&W[(size_t)(k0 + r) * 1024 + n0 + c4];
        Ls[r][c4] = t.x; Ls[r][c4 + 1] = t.y; Ls[r][c4 + 2] = t.z; Ls[r][c4 + 3] = t.w;
    }
    __syncthreads();
    const int n = tid >> 2, j0 = (tid & 3) * 16;
    unsigned uh[8], ul[8];
#pragma unroll
    for (int j = 0; j < 8; ++j) {
        float a = Ls[j0 + 2 * j][n], b = Ls[j0 + 2 * j + 1][n];
        unsigned h = pkbf(a, b);
        float ra = a - __uint_as_float(h << 16);
        float rb = b - __uint_as_float(h & 0xffff0000u);
        uh[j] = h; ul[j] = pkbf(ra, rb);
    }
    unsigned short* op = dst + (size_t)(n0 + n) * 1024 + k0 + j0;
    uint4 o;
    o.x = uh[0]; o.y = uh[1]; o.z = uh[2]; o.w = uh[3]; *(uint4*)op = o;
    o.x = uh[4]; o.y = uh[5]; o.z = uh[6]; o.w = uh[7]; *(uint4*)(op + 8) = o;
    op += 1048576;
    o.x = ul[0]; o.y = ul[1]; o.z = ul[2]; o.w = ul[3]; *(uint4*)op = o;
    o.x = ul[4]; o.y = ul[5]; o.z = ul[6]; o.w = ul[7]; *(uint4*)(op + 8) = o;
}

// ---------------- XT transpose+split: dst[(b*L+l)][e] (hi, lo planes) <- XT[b][e][l]
__global__ __launch_bounds__(256) void xtt_kernel(
    const float* __restrict__ XT, unsigned short* __restrict__ dst)
{
    __shared__ float Ls[64][65];
    const int tid = threadIdx.x;
    const int b = blockIdx.z, e0 = blockIdx.y * 64, l0 = blockIdx.x * 64;
#pragma unroll
    for (int i = 0; i < 4; ++i) {
        int idx = i * 256 + tid;
        int r = idx >> 4, c4 = (idx & 15) * 4;
        float4 t = *(const float4*)&XT[((size_t)b * 1024 + e0 + r) * 4096 + l0 + c4];
        Ls[r][c4] = t.x; Ls[r][c4 + 1] = t.y; Ls[r][c4 + 2] = t.z; Ls[r][c4 + 3] = t.w;
    }
    __syncthreads();
    const int l = tid >> 2, j0 = (tid & 3) * 16;
    unsigned uh[8], ul[8];
#pragma unroll
    for (int j = 0; j < 8; ++j) {
        float a = Ls[j0 + 2 * j][l], b2 = Ls[j0 + 2 * j + 1][l];
        unsigned h = pkbf(a, b2);
        float ra = a - __uint_as_float(h << 16);
        float rb = b2 - __uint_as_float(h & 0xffff0000u);
        uh[j] = h; ul[j] = pkbf(ra, rb);
    }
    unsigned short* op = dst + ((size_t)(b * 4096 + l0 + l)) * 1024 + e0 + j0;
    uint4 o;
    o.x = uh[0]; o.y = uh[1]; o.z = uh[2]; o.w = uh[3]; *(uint4*)op = o;
    o.x = uh[4]; o.y = uh[5]; o.z = uh[6]; o.w = uh[7]; *(uint4*)(op + 8) = o;
    op += 16777216;
    o.x = ul[0]; o.y = ul[1]; o.z = ul[2]; o.w = ul[3]; *(uint4*)op = o;
    o.x = ul[4]; o.y = ul[5]; o.z = ul[6]; o.w = ul[7]; *(uint4*)(op + 8) = o;
}

// ---------------- Split-bf16 MFMA GEMM: C[m][n] = sum_k A[m][k]*Bt[n][k] + bias[n]
template<bool ASPLIT, bool FULL4>
__global__ __launch_bounds__(256) void mm_split(
    const float* __restrict__ Af32, const unsigned short* __restrict__ Abf,
    const unsigned short* __restrict__ Bt,
    const float* __restrict__ bias, float* __restrict__ C)
{
    __shared__ __align__(16) unsigned short Ah[128 * 64];
    __shared__ __align__(16) unsigned short Al[128 * 64];
    __shared__ __align__(16) unsigned short Bh[128 * 64];
    __shared__ __align__(16) unsigned short Bl[128 * 64];
    const int tid = threadIdx.x;
    const int m0 = blockIdx.y * 128, n0 = blockIdx.x * 128;
    const int lane = tid & 63, w = tid >> 6;
    const int lq = lane & 31, hi = lane >> 5;
    const int wm = (w >> 1) * 64, wn = (w & 1) * 64;

    f32x16 acc[2][2];
#pragma unroll
    for (int i = 0; i < 2; ++i)
#pragma unroll
        for (int j = 0; j < 2; ++j)
#pragma unroll
            for (int r = 0; r < 16; ++r) acc[i][j][r] = 0.f;

    for (int kb = 0; kb < 1024; kb += 64) {
        __syncthreads();
        if constexpr (ASPLIT) {
#pragma unroll
            for (int i = 0; i < 8; ++i) {
                int idx = i * 256 + tid;
                int r = idx >> 4, fq = idx & 15;
                float4 a = *(const float4*)(Af32 + (size_t)(m0 + r) * 1024 + kb + fq * 4);
                unsigned h0 = pkbf(a.x, a.y), h1 = pkbf(a.z, a.w);
                float rx = a.x - __uint_as_float(h0 << 16);
                float ry = a.y - __uint_as_float(h0 & 0xffff0000u);
                float rz = a.z - __uint_as_float(h1 << 16);
                float rw = a.w - __uint_as_float(h1 & 0xffff0000u);
                unsigned l0 = pkbf(rx, ry), l1 = pkbf(rz, rw);
                int boff = r * 128 + ((fq * 8) ^ ((r & 7) << 4));
                uint2 th; th.x = h0; th.y = h1;
                uint2 tl; tl.x = l0; tl.y = l1;
                *(uint2*)((char*)Ah + boff) = th;
                *(uint2*)((char*)Al + boff) = tl;
            }
        } else {
#pragma unroll
            for (int p = 0; p < 2; ++p) {
                const unsigned short* ap = Abf + (size_t)p * 16777216 + (size_t)m0 * 1024 + kb;
                unsigned short* dst = p ? Al : Ah;
#pragma unroll
                for (int i = 0; i < 4; ++i) {
                    int idx = i * 256 + tid;
                    int r = idx >> 3, uq = idx & 7;
                    uint4 d = *(const uint4*)(ap + (size_t)r * 1024 + uq * 8);
                    *(uint4*)((char*)dst + r * 128 + ((uq * 16) ^ ((r & 7) << 4))) = d;
                }
            }
        }
#pragma unroll
        for (int p = 0; p < 2; ++p) {
            const unsigned short* bp = Bt + (size_t)p * 1048576 + (size_t)n0 * 1024 + kb;
            unsigned short* dst = p ? Bl : Bh;
#pragma unroll
            for (int i = 0; i < 4; ++i) {
                int idx = i * 256 + tid;
                int r = idx >> 3, uq = idx & 7;
                uint4 d = *(const uint4*)(bp + (size_t)r * 1024 + uq * 8);
                *(uint4*)((char*)dst + r * 128 + ((uq * 16) ^ ((r & 7) << 4))) = d;
            }
        }
        __syncthreads();
#pragma unroll
        for (int kt = 0; kt < 4; ++kt) {
            bf16x8 fah[2], fal[2], fbh[2], fbl[2];
            const int cb = kt * 32 + hi * 16;
#pragma unroll
            for (int mb = 0; mb < 2; ++mb) {
                int r = wm + mb * 32 + lq;
                int off = r * 128 + (cb ^ ((r & 7) << 4));
                fah[mb] = *(const bf16x8*)((const char*)Ah + off);
                fal[mb] = *(const bf16x8*)((const char*)Al + off);
            }
#pragma unroll
            for (int nb = 0; nb < 2; ++nb) {
                int r = wn + nb * 32 + lq;
                int off = r * 128 + (cb ^ ((r & 7) << 4));
                fbh[nb] = *(const bf16x8*)((const char*)Bh + off);
                fbl[nb] = *(const bf16x8*)((const char*)Bl + off);
            }
#pragma unroll
            for (int mb = 0; mb < 2; ++mb)
#pragma unroll
                for (int nb = 0; nb < 2; ++nb) {
                    acc[mb][nb] = __builtin_amdgcn_mfma_f32_32x32x16_bf16(fah[mb], fbh[nb], acc[mb][nb], 0, 0, 0);
                    acc[mb][nb] = __builtin_amdgcn_mfma_f32_32x32x16_bf16(fah[mb], fbl[nb], acc[mb][nb], 0, 0, 0);
                    acc[mb][nb] = __builtin_amdgcn_mfma_f32_32x32x16_bf16(fal[mb], fbh[nb], acc[mb][nb], 0, 0, 0);
                    if constexpr (FULL4)
                        acc[mb][nb] = __builtin_amdgcn_mfma_f32_32x32x16_bf16(fal[mb], fbl[nb], acc[mb][nb], 0, 0, 0);
                }
        }
    }
#pragma unroll
    for (int mb = 0; mb < 2; ++mb)
#pragma unroll
        for (int nb = 0; nb < 2; ++nb) {
            int n = n0 + wn + nb * 32 + lq;
            float bn = bias[n];
#pragma unroll
            for (int r = 0; r < 16; ++r) {
                int m = m0 + wm + mb * 32 + (r & 3) + 8 * (r >> 2) + 4 * hi;
                C[(size_t)m * 1024 + n] = acc[mb][nb][r] + bn;
            }
        }
}

// ---------------- V transpose to bf16: vth[b][h][d][L] <- v[b][l][h*64+d] ----
__global__ __launch_bounds__(256) void vt_kernel(
    const float* __restrict__ v, unsigned short* __restrict__ vth)
{
    const int b = blockIdx.z, h = blockIdx.y, l0 = blockIdx.x * 64;
    const int tid = threadIdx.x;
    __shared__ float Ls[64][65];
#pragma unroll
    for (int it = 0; it < 4; ++it) {
        int idx = it * 256 + tid;
        int r = idx >> 4, c4 = (idx & 15) * 4;
        float4 t = *(const float4*)&v[((size_t)b * Lz + l0 + r) * Dz + h * DHz + c4];
        Ls[r][c4] = t.x; Ls[r][c4 + 1] = t.y; Ls[r][c4 + 2] = t.z; Ls[r][c4 + 3] = t.w;
    }
    __syncthreads();
    const int d = tid >> 2, j0 = (tid & 3) * 16;
    unsigned u[8];
#pragma unroll
    for (int j = 0; j < 8; ++j)
        u[j] = pkbf(Ls[j0 + 2 * j][d], Ls[j0 + 2 * j + 1][d]);
    unsigned short* op = vth + ((size_t)(b * Hz + h) * 64 + d) * Lz + l0 + j0;
    uint4 o0; o0.x = u[0]; o0.y = u[1]; o0.z = u[2]; o0.w = u[3];
    uint4 o1; o1.x = u[4]; o1.y = u[5]; o1.z = u[6]; o1.w = u[7];
    *(uint4*)op = o0;
    *(uint4*)(op + 8) = o1;
}

// ---------------- sigma(k) precompute: sk[i] = sigmaf(k[i]) (bit-identical values)
__global__ __launch_bounds__(256) void sigk_kernel(
    const float* __restrict__ k, float* __restrict__ sk)
{
    const size_t n4 = (size_t)Bz * Lz * Dz / 4;
    size_t i = (size_t)blockIdx.x * 256 + threadIdx.x;
    const size_t stride = (size_t)gridDim.x * 256;
    for (; i < n4; i += stride) {
        float4 t = ((const float4*)k)[i];
        t.x = sigmaf(t.x); t.y = sigmaf(t.y); t.z = sigmaf(t.z); t.w = sigmaf(t.w);
        ((float4*)sk)[i] = t;
    }
}

// ---------------- MFMA local attention; writes (1-g)*dot into XT[b][e][l] ----
__global__ __launch_bounds__(256) void attn_kernel(
    const float* __restrict__ q, const float* __restrict__ k,
    const unsigned short* __restrict__ vth,
    const float* __restrict__ beta, float* __restrict__ XT)
{
    const int bh = blockIdx.z; const int b = bh >> 4, h = bh & 15;
    const int c = blockIdx.y;
    const int qt = blockIdx.x;            // q-tile 0..3 (128 rows each)
    const int tid = threadIdx.x;
    const int lane = tid & 63;
    const int w = tid >> 6;
    const int lq = lane & 31;
    const int hi = lane >> 5;
    const float g = 1.f / (1.f + __expf(-beta[0]));

    __shared__ __align__(16) unsigned short Qs[128 * 64];  // bf16, swizzled rows of 128B
    __shared__ __align__(16) unsigned short Ks[64 * 64];   // bf16 [t][d]
    __shared__ __align__(16) unsigned short Vs[64 * 64];   // bf16 [d][t]
    __shared__ float lsum_lds[128];

    const size_t rowb = (size_t)b * Lz * Dz + (size_t)h * DHz;

    // ---- stage Q tile (128 rows) fp32 -> bf16, XOR-swizzled ----
    {
        const int r = tid >> 2, c4 = tid & 3;
#pragma unroll
        for (int p = 0; p < 2; ++p) {
            int rr = p * 64 + r;
            const float* qp = q + rowb + (size_t)(c * Sz + qt * 128 + rr) * Dz + c4 * 16;
            float4 f0 = ((const float4*)qp)[0];
            float4 f1 = ((const float4*)qp)[1];
            float4 f2 = ((const float4*)qp)[2];
            float4 f3 = ((const float4*)qp)[3];
            uint4 u0, u1;
            u0.x = pkbf(f0.x, f0.y); u0.y = pkbf(f0.z, f0.w);
            u0.z = pkbf(f1.x, f1.y); u0.w = pkbf(f1.z, f1.w);
            u1.x = pkbf(f2.x, f2.y); u1.y = pkbf(f2.z, f2.w);
            u1.z = pkbf(f3.x, f3.y); u1.w = pkbf(f3.z, f3.w);
            int base = rr * 128;
            *(uint4*)((char*)Qs + base + ((c4 * 32)      ^ ((rr & 7) << 4))) = u0;
            *(uint4*)((char*)Qs + base + ((c4 * 32 + 16) ^ ((rr & 7) << 4))) = u1;
        }
    }
    __syncthreads();
    // Q B-fragments: lane holds Q[q = w*32+lq][d = 8*hi + i + 16*ck]
    bf16x8 qf[4];
#pragma unroll
    for (int ck = 0; ck < 4; ++ck) {
        int rr = w * 32 + lq;
        qf[ck] = *(const bf16x8*)((const char*)Qs + rr * 128 + ((ck * 32 + hi * 16) ^ ((rr & 7) << 4)));
    }

    f32x16 acc0, acc1;
#pragma unroll
    for (int r = 0; r < 16; ++r) { acc0[r] = 0.f; acc1[r] = 0.f; }
    float lsum = 0.f;

    for (int kt = 0; kt < 8; ++kt) {
        __syncthreads();
        // ---- stage K (fp32->bf16, [t][d]) and V (bf16 from vth, [d][t]), swizzled ----
        {
            const int r = tid >> 2, c4 = tid & 3;
            const float* kp = k + rowb + (size_t)(c * Sz + kt * 64 + r) * Dz + c4 * 16;
            float4 f0 = ((const float4*)kp)[0];
            float4 f1 = ((const float4*)kp)[1];
            float4 f2 = ((const float4*)kp)[2];
            float4 f3 = ((const float4*)kp)[3];
            uint4 u0, u1;
            u0.x = pkbf(f0.x, f0.y); u0.y = pkbf(f0.z, f0.w);
            u0.z = pkbf(f1.x, f1.y); u0.w = pkbf(f1.z, f1.w);
            u1.x = pkbf(f2.x, f2.y); u1.y = pkbf(f2.z, f2.w);
            u1.z = pkbf(f3.x, f3.y); u1.w = pkbf(f3.z, f3.w);
            int base = r * 128;
            *(uint4*)((char*)Ks + base + ((c4 * 32)      ^ ((r & 7) << 4))) = u0;
            *(uint4*)((char*)Ks + base + ((c4 * 32 + 16) ^ ((r & 7) << 4))) = u1;
            // V: row index r is d, columns are t (already bf16 in vth)
            const unsigned short* vp = vth + ((size_t)(b * Hz + h) * 64 + r) * Lz + c * Sz + kt * 64 + c4 * 16;
            uint4 v0 = ((const uint4*)vp)[0];
            uint4 v1 = ((const uint4*)vp)[1];
            *(uint4*)((char*)Vs + base + ((c4 * 32)      ^ ((r & 7) << 4))) = v0;
            *(uint4*)((char*)Vs + base + ((c4 * 32 + 16) ^ ((r & 7) << 4))) = v1;
        }
        __syncthreads();

        bf16x8 pA[4];
#pragma unroll
        for (int tb = 0; tb < 2; ++tb) {
            f32x16 pt;
#pragma unroll
            for (int r = 0; r < 16; ++r) pt[r] = 0.f;
#pragma unroll
            for (int ck = 0; ck < 4; ++ck) {
                int rr = tb * 32 + lq;
                bf16x8 ka = *(const bf16x8*)((const char*)Ks + rr * 128 + ((ck * 32 + hi * 16) ^ ((rr & 7) << 4)));
                // Pt[t][q] += K[t][d] * Q[q][d]
                pt = __builtin_amdgcn_mfma_f32_32x32x16_bf16(ka, qf[ck], pt, 0, 0, 0);
            }
            // p = exp(logit*scale); lane covers t = tb*32 + (r&3)+8*(r>>2)+4*hi for q = w*32+lq
            float p[16];
#pragma unroll
            for (int r = 0; r < 16; ++r) { p[r] = __expf(pt[r] * 0.125f); lsum += p[r]; }
            // repack D-layout (col=q) -> A-layout (m=q, k=t) via cvt_pk + permlane32_swap
#pragma unroll
            for (int cc = 0; cc < 2; ++cc) {
                unsigned u0 = pkbf(p[8 * cc + 0], p[8 * cc + 1]);
                unsigned u1 = pkbf(p[8 * cc + 2], p[8 * cc + 3]);
                unsigned u2 = pkbf(p[8 * cc + 4], p[8 * cc + 5]);
                unsigned u3 = pkbf(p[8 * cc + 6], p[8 * cc + 7]);
                asm volatile("v_permlane32_swap_b32 %0, %1" : "+v"(u0), "+v"(u2));
                asm volatile("v_permlane32_swap_b32 %0, %1" : "+v"(u1), "+v"(u3));
                union { unsigned u[4]; bf16x8 v; } pa;
                pa.u[0] = u0; pa.u[1] = u1; pa.u[2] = u2; pa.u[3] = u3;
                pA[tb * 2 + cc] = pa.v;
            }
        }
        // PV: out[q][d] += P[q][t] * V[t][d]
#pragma unroll
        for (int ck = 0; ck < 4; ++ck) {
            int r0 = lq;
            bf16x8 vf0 = *(const bf16x8*)((const char*)Vs + r0 * 128 + ((ck * 32 + hi * 16) ^ ((r0 & 7) << 4)));
            acc0 = __builtin_amdgcn_mfma_f32_32x32x16_bf16(pA[ck], vf0, acc0, 0, 0, 0);
            int r1 = 32 + lq;
            bf16x8 vf1 = *(const bf16x8*)((const char*)Vs + r1 * 128 + ((ck * 32 + hi * 16) ^ ((r1 & 7) << 4)));
            acc1 = __builtin_amdgcn_mfma_f32_32x32x16_bf16(pA[ck], vf1, acc1, 0, 0, 0);
        }
    }

    // finish row sums: lane and lane^32 each hold half the t's of row q=w*32+lq
    lsum += __shfl_xor(lsum, 32);
    if (hi == 0) lsum_lds[w * 32 + lq] = lsum;
    __syncthreads();

    const float invg = 1.f - g;
#pragma unroll
    for (int r = 0; r < 16; ++r) {
        int ql = (r & 3) + 8 * (r >> 2) + 4 * hi;
        float sc = invg / lsum_lds[w * 32 + ql];
        int s = qt * 128 + w * 32 + ql;
        int e = c * 128 + h * 8 + (s >> 6);
        float* xp = XT + ((size_t)b * Dz + e) * Lz + (s & 63) * 64;
        xp[lq]      = acc0[r] * sc;
        xp[32 + lq] = acc1[r] * sc;
    }
}

// ---------------- Scan phase 1: evolve M,z; store per-segment prefixes ----
// grid: 512 blocks = bh(64) x esplit(8); block 256 threads (el=tid&7, rs=tid>>3).
// PRE: ksrc holds precomputed sigma(k) (pure copy staging); else raw k (apply sigmaf).
// Bit-identical arithmetic to r4: every output element keeps its exact FLOP
// sequence (d-order, sl 0..63 order, chunk order, segment order). Changes are
// indexing-only: vsT e-major layout, unrolled mdelta, register prefetch.
#define S1_LOAD(S0_) do {                                                            \
    _Pragma("unroll")                                                                \
    for (int it_ = 0; it_ < 4; ++it_) {                                              \
        int r_ = it_ * 16 + (tid >> 4);                                              \
        ka[it_] = *(const float4*)(ksrc + boff + (size_t)((S0_) + r_) * Dz + (tid & 15) * 4); \
    }                                                                                \
    va = *(const float2*)(v + boff + (size_t)((S0_) + (tid >> 2)) * Dz + es * 8 + (tid & 3) * 2); \
} while (0)

template<bool PRE>
__global__ __launch_bounds__(256) void scan_s1(
    const float* __restrict__ ksrc, const float* __restrict__ v,
    float* __restrict__ Mpre, float* __restrict__ zpre)
{
    const int bx = blockIdx.x;
    const int bh = bx >> 3, es = bx & 7;
    const int b = bh >> 4, h = bh & 15;
    const int tid = threadIdx.x;
    const int el = tid & 7;           // e-local 0..7
    const int rs = tid >> 3;          // 0..31
    const int eg = es * 8 + el;       // e within head, 0..63

    __shared__ float ks[64][68];      // sigma(k) rows
    __shared__ float vsT[8][68];      // val buffer, e-major: vsT[e][sl]

    float Mreg[64];                   // column eg of M
#pragma unroll
    for (int d = 0; d < 64; ++d) Mreg[d] = 0.f;
    float zreg = 0.f;

    const size_t boff = (size_t)b * Lz * Dz + h * DHz;

    for (int c = 0; c < Cz; ++c) {
        // store prefix (pre-segment M, z) for S2
        {
            float* mp = Mpre + ((size_t)(bh * Cz + c) * 64) * 64;
#pragma unroll
            for (int j = 0; j < 2; ++j) {
                int d = rs * 2 + j;
                mp[(size_t)d * 64 + eg] = Mreg[d];
            }
            if (rs == 0) zpre[(size_t)(bh * Cz + c) * 64 + eg] = zreg;
        }
        float mdelta0 = 0.f, mdelta1 = 0.f;
        float zd = 0.f;

        float4 ka[4]; float2 va;
        S1_LOAD(c * Sz);                      // prologue loads for ch=0

        for (int ch = 0; ch < 8; ++ch) {
            __syncthreads();                  // prev phase done reading LDS
            // stage sigma(k) rows (copy if PRE) + v slice (e-major)
#pragma unroll
            for (int it = 0; it < 4; ++it) {
                int r = it * 16 + (tid >> 4), f = (tid & 15) * 4;
                float4 t = ka[it];
                if constexpr (!PRE) {
                    t.x = sigmaf(t.x); t.y = sigmaf(t.y);
                    t.z = sigmaf(t.z); t.w = sigmaf(t.w);
                }
                *(float4*)&ks[r][f] = t;
            }
            {
                int r = tid >> 2, f = (tid & 3) * 2;
                vsT[f][r] = va.x; vsT[f + 1][r] = va.y;
            }
            __syncthreads();
            // val = v - (sigma(k)@M)/(ssk*z+eps), thread owns (sl=rs*2+j, el)
#pragma unroll
            for (int j = 0; j < 2; ++j) {
                const int sl = rs * 2 + j;
                float numk = 0.f, ssk = 0.f;
#pragma unroll
                for (int d = 0; d < 64; d += 4) {
                    float4 kk = *(const float4*)&ks[sl][d];
                    numk += kk.x * Mreg[d] + kk.y * Mreg[d + 1]
                          + kk.z * Mreg[d + 2] + kk.w * Mreg[d + 3];
                    ssk += kk.x + kk.y + kk.z + kk.w;
                }
                vsT[el][sl] = vsT[el][sl] - numk / (ssk * zreg + 1e-6f);
            }
            // issue next chunk's global loads (overlap with mdelta phase)
            if (ch < 7) S1_LOAD(c * Sz + (ch + 1) * 64);
            __syncthreads();
            // mdelta[d=rs*2+j][eg] += sum_sl sigma(k)[sl][d]*val[sl][eg]; z delta.
            // sl order 0..63 preserved exactly (unrolled).
#pragma unroll
            for (int sl4 = 0; sl4 < 16; ++sl4) {
                float4 vv4 = *(const float4*)&vsT[el][sl4 * 4];
                {
                    const int sl = sl4 * 4;
                    float2 kk = *(const float2*)&ks[sl][rs * 2];
                    mdelta0 += kk.x * vv4.x; mdelta1 += kk.y * vv4.x;
                    zd += ks[sl][eg];
                }
                {
                    const int sl = sl4 * 4 + 1;
                    float2 kk = *(const float2*)&ks[sl][rs * 2];
                    mdelta0 += kk.x * vv4.y; mdelta1 += kk.y * vv4.y;
                    zd += ks[sl][eg];
                }
                {
                    const int sl = sl4 * 4 + 2;
                    float2 kk = *(const float2*)&ks[sl][rs * 2];
                    mdelta0 += kk.x * vv4.z; mdelta1 += kk.y * vv4.z;
                    zd += ks[sl][eg];
                }
                {
                    const int sl = sl4 * 4 + 3;
                    float2 kk = *(const float2*)&ks[sl][rs * 2];
                    mdelta0 += kk.x * vv4.w; mdelta1 += kk.y * vv4.w;
                    zd += ks[sl][eg];
                }
            }
        }
        // apply deltas: exchange mdelta columns via vsT
        __syncthreads();
        vsT[el][rs * 2]     = mdelta0;
        vsT[el][rs * 2 + 1] = mdelta1;
        __syncthreads();
#pragma unroll
        for (int d = 0; d < 64; d += 4) {
            float4 md = *(const float4*)&vsT[el][d];
            Mreg[d] += md.x; Mreg[d + 1] += md.y;
            Mreg[d + 2] += md.z; Mreg[d + 3] += md.w;
        }
        zreg += zd;
    }
}

// ---------------- Scan phase 2: A-readout from prefixes; XT += g*A ----
__global__ __launch_bounds__(256) void scan_s2(
    const float* __restrict__ q, const float* __restrict__ Mpre,
    const float* __restrict__ zpre, const float* __restrict__ beta,
    float* __restrict__ XT)
{
    const int bh = blockIdx.z; const int b = bh >> 4, h = bh & 15;
    const int c = blockIdx.y;
    const int tile = blockIdx.x;          // 0..7
    const int tid = threadIdx.x;
    const int lane = tid & 63;            // e
    const int w = tid >> 6;               // wave 0..3
    const float g = 1.f / (1.f + __expf(-beta[0]));

    __shared__ float qs[64][68];

    float Mreg[64];
    const float* mp = Mpre + ((size_t)(bh * Cz + c) * 64) * 64;
#pragma unroll
    for (int d = 0; d < 64; ++d) Mreg[d] = mp[(size_t)d * 64 + lane];
    const float zv = zpre[(size_t)(bh * Cz + c) * 64 + lane];

    const size_t boff = (size_t)b * Lz * Dz + h * DHz;
    const int s0 = c * Sz + tile * 64;
#pragma unroll
    for (int it = 0; it < 4; ++it) {
        int idx = it * 256 + tid;
        int r = idx >> 4, f = (idx & 15) * 4;
        float4 t = *(const float4*)(q + boff + (size_t)(s0 + r) * Dz + f);
        qs[r][f + 0] = sigmaf(t.x); qs[r][f + 1] = sigmaf(t.y);
        qs[r][f + 2] = sigmaf(t.z); qs[r][f + 3] = sigmaf(t.w);
    }
    __syncthreads();

    const int e_out = c * 128 + h * 8 + tile;
    float* xp = XT + ((size_t)b * Dz + e_out) * Lz;
    for (int i = 0; i < 16; ++i) {
        const int sl = w * 16 + i;
        float num = 0.f, ssq = 0.f;
#pragma unroll
        for (int d = 0; d < 64; d += 4) {
            float4 qq = *(const float4*)&qs[sl][d];
            num += qq.x * Mreg[d] + qq.y * Mreg[d + 1]
                 + qq.z * Mreg[d + 2] + qq.w * Mreg[d + 3];
            ssq += qq.x + qq.y + qq.z + qq.w;
        }
        float A = num / (ssq * zv + 1e-6f);
        size_t xoff = (size_t)sl * 64 + lane;
        xp[xoff] += g * A;
    }
}

extern "C" void kernel_launch(void* const* d_in, const int* in_sizes, int n_in,
                              void* d_out, int out_size, void* d_ws, size_t ws_size,
                              hipStream_t stream)
{
    (void)in_sizes; (void)n_in; (void)out_size;
    const float* query  = (const float*)d_in[0];
    const float* key_in = (const float*)d_in[1];
    const float* value  = (const float*)d_in[2];
    const float* Wq = (const float*)d_in[3];
    const float* bq = (const float*)d_in[4];
    const float* Wk = (const float*)d_in[5];
    const float* bk = (const float*)d_in[6];
    const float* Wv = (const float*)d_in[7];
    const float* bv = (const float*)d_in[8];
    const float* Wo = (const float*)d_in[9];
    const float* bo = (const float*)d_in[10];
    const float* beta = (const float*)d_in[11];
    float* out = (float*)d_out;

    const size_t NE = (size_t)Bz * Lz * Dz;            // 16,777,216 per buffer
    const size_t NM = (size_t)64 * Cz * 64 * 64;       // M prefixes
    const size_t NZ = (size_t)64 * Cz * 64;            // z prefixes
    float* qb = (float*)d_ws;
    float* kb = qb + NE;
    float* vb = kb + NE;
    float* Mpre = vb + NE;
    float* zpre = Mpre + NM;
    float* XT = vb;                       // vb dead after scan_s1 -> reused as XT
    float* sk = zpre + NZ;                // sigma(k), only if workspace allows
    const bool big = ws_size >= (4 * NE + NM + NZ) * sizeof(float);

    // d_out (64MB) scratch until final GEMM: Wt q/k/v (12MB) + vth (32MB)
    unsigned short* u0  = (unsigned short*)d_out;
    unsigned short* Wtq = u0;
    unsigned short* Wtk = u0 + 2 * 1048576;
    unsigned short* Wtv = u0 + 4 * 1048576;
    unsigned short* vth = u0 + 6 * 1048576;
    unsigned short* Wto = (unsigned short*)kb;   // kb dead after attn
    unsigned short* XTt = (unsigned short*)qb;   // qb dead after scan_s2 (64MB = 2 planes)

    wt_kernel<<<dim3(16, 16), 256, 0, stream>>>(Wq, Wtq);
    wt_kernel<<<dim3(16, 16), 256, 0, stream>>>(Wk, Wtk);
    wt_kernel<<<dim3(16, 16), 256, 0, stream>>>(Wv, Wtv);
    mm_split<true, true><<<dim3(8, 128), 256, 0, stream>>>(query,  nullptr, Wtq, bq, qb);
    mm_split<true, true><<<dim3(8, 128), 256, 0, stream>>>(key_in, nullptr, Wtk, bk, kb);
    mm_split<true, true><<<dim3(8, 128), 256, 0, stream>>>(value,  nullptr, Wtv, bv, vb);
    vt_kernel<<<dim3(Lz / 64, Hz, Bz), 256, 0, stream>>>(vb, vth);
    if (big) {
        sigk_kernel<<<dim3(2048), 256, 0, stream>>>(kb, sk);
        scan_s1<true><<<dim3(512), 256, 0, stream>>>(sk, vb, Mpre, zpre);
    } else {
        scan_s1<false><<<dim3(512), 256, 0, stream>>>(kb, vb, Mpre, zpre);
    }
    attn_kernel<<<dim3(4, Cz, Bz * Hz), 256, 0, stream>>>(qb, kb, vth, beta, XT);
    scan_s2<<<dim3(8, Cz, Bz * Hz), 256, 0, stream>>>(qb, Mpre, zpre, beta, XT);
    wt_kernel<<<dim3(16, 16), 256, 0, stream>>>(Wo, Wto);
    xtt_kernel<<<dim3(Lz / 64, Dz / 64, Bz), 256, 0, stream>>>(XT, XTt);
    mm_split<false, false><<<dim3(8, 128), 256, 0, stream>>>(nullptr, XTt, Wto, bo, out);
}